// Round 1
// baseline (1741.049 us; speedup 1.0000x reference)
//
#include <hip/hip_runtime.h>

// Problem constants (fixed by reference)
constexpr int NN   = 20000;          // nodes
constexpr int NE   = 320000;         // edges (before self-loops)
constexpr int NTOT = NE + NN;        // edges incl self-loops
constexpr int FIN  = 128;
constexpr int HID  = 256;
constexpr int NG   = 128;            // graphs
constexpr int NCLS = 10;

// ---- ordered-uint encoding for float atomicMax ----
__device__ __forceinline__ unsigned fenc(float f) {
  unsigned b = __float_as_uint(f);
  return (b & 0x80000000u) ? ~b : (b | 0x80000000u);
}
__device__ __forceinline__ float fdec(unsigned u) {
  return (u & 0x80000000u) ? __uint_as_float(u & 0x7fffffffu) : __uint_as_float(~u);
}

// ---- per-column mean/var partials (blockDim.x == C) ----
__global__ void colstats_kernel(const float* __restrict__ X, int M,
                                float* __restrict__ sum, float* __restrict__ sumsq) {
  int C = blockDim.x;
  int c = threadIdx.x;
  float s = 0.f, ss = 0.f;
  for (int r = blockIdx.x; r < M; r += gridDim.x) {
    float v = X[(size_t)r * C + c];
    s += v; ss += v * v;
  }
  atomicAdd(&sum[c], s);
  atomicAdd(&sumsq[c], ss);
}

__global__ void finalize_stats(const float* __restrict__ sum, const float* __restrict__ sumsq,
                               const float* __restrict__ g, const float* __restrict__ b,
                               float invM, float* __restrict__ scale, float* __restrict__ shift) {
  int c = threadIdx.x;
  float m = sum[c] * invM;
  float v = sumsq[c] * invM - m * m;
  float sc = g[c] * rsqrtf(v + 1e-5f);
  scale[c] = sc;
  shift[c] = b[c] - m * sc;
}

// ---- f32 GEMM: C = [relu]( (A*scale+shift) @ B + bias ), tiles 64x64x16 ----
__global__ __launch_bounds__(256) void gemm_kernel(
    const float* __restrict__ A, const float* __restrict__ B,
    const float* __restrict__ scale, const float* __restrict__ shift,
    const float* __restrict__ bias, float* __restrict__ C,
    int M, int K, int N, int do_relu) {
  __shared__ float As[16][65];
  __shared__ float Bs[16][64];
  int tid = threadIdx.x;
  int tx = tid & 15, ty = tid >> 4;
  int bm = blockIdx.x * 64, bn = blockIdx.y * 64;
  int ar = tid >> 2, ak = (tid & 3) << 2;   // A tile: 64 rows x 16 k
  int bkr = tid >> 4, bno = (tid & 15) << 2; // B tile: 16 k x 64 n
  float acc[4][4] = {};
  for (int k0 = 0; k0 < K; k0 += 16) {
    float4 av = make_float4(0.f, 0.f, 0.f, 0.f);
    int arow = bm + ar;
    if (arow < M)
      av = *reinterpret_cast<const float4*>(A + (size_t)arow * K + k0 + ak);
    if (scale) {
      float4 sc = *reinterpret_cast<const float4*>(scale + k0 + ak);
      float4 sh = *reinterpret_cast<const float4*>(shift + k0 + ak);
      av.x = av.x * sc.x + sh.x;
      av.y = av.y * sc.y + sh.y;
      av.z = av.z * sc.z + sh.z;
      av.w = av.w * sc.w + sh.w;
    }
    As[ak + 0][ar] = av.x;
    As[ak + 1][ar] = av.y;
    As[ak + 2][ar] = av.z;
    As[ak + 3][ar] = av.w;
    float4 bv = *reinterpret_cast<const float4*>(B + (size_t)(k0 + bkr) * N + bn + bno);
    *reinterpret_cast<float4*>(&Bs[bkr][bno]) = bv;
    __syncthreads();
#pragma unroll
    for (int k = 0; k < 16; ++k) {
      float a[4], bb[4];
#pragma unroll
      for (int i = 0; i < 4; ++i) a[i] = As[k][ty * 4 + i];
#pragma unroll
      for (int j = 0; j < 4; ++j) bb[j] = Bs[k][tx * 4 + j];
#pragma unroll
      for (int i = 0; i < 4; ++i)
#pragma unroll
        for (int j = 0; j < 4; ++j) acc[i][j] += a[i] * bb[j];
    }
    __syncthreads();
  }
#pragma unroll
  for (int i = 0; i < 4; ++i) {
    int row = bm + ty * 4 + i;
    if (row >= M) continue;
#pragma unroll
    for (int j = 0; j < 4; ++j) {
      int col = bn + tx * 4 + j;
      float v = acc[i][j] + (bias ? bias[col] : 0.f);
      if (do_relu) v = fmaxf(v, 0.f);
      C[(size_t)row * N + col] = v;
    }
  }
}

// ---- per-node attention logits: als/ald [N,4], one wave per node ----
__global__ void attn_logits_kernel(const float* __restrict__ xp,
                                   const float* __restrict__ asrc,
                                   const float* __restrict__ adst,
                                   float* __restrict__ als, float* __restrict__ ald) {
  int wave = (blockIdx.x * blockDim.x + threadIdx.x) >> 6;
  int lane = threadIdx.x & 63;
  if (wave >= NN) return;
  const float* row = xp + (size_t)wave * HID;
#pragma unroll
  for (int h = 0; h < 4; ++h) {
    float v = row[h * 64 + lane];
    float s = v * asrc[h * 64 + lane];
    float d = v * adst[h * 64 + lane];
#pragma unroll
    for (int off = 32; off > 0; off >>= 1) {
      s += __shfl_down(s, off);
      d += __shfl_down(d, off);
    }
    if (lane == 0) {
      als[wave * 4 + h] = s;
      ald[wave * 4 + h] = d;
    }
  }
}

__device__ __forceinline__ void edge_sd(const int* __restrict__ ei, int e, int& s, int& d) {
  if (e < NE) { s = ei[e]; d = ei[NE + e]; }
  else        { s = e - NE; d = s; }
}

__global__ void edge_max_kernel(const int* __restrict__ ei,
                                const float* __restrict__ als, const float* __restrict__ ald,
                                unsigned* __restrict__ mx) {
  int e = blockIdx.x * blockDim.x + threadIdx.x;
  if (e >= NTOT) return;
  int s, d; edge_sd(ei, e, s, d);
#pragma unroll
  for (int h = 0; h < 4; ++h) {
    float v = als[s * 4 + h] + ald[d * 4 + h];
    v = v > 0.f ? v : 0.2f * v;
    atomicMax(&mx[d * 4 + h], fenc(v));
  }
}

__global__ void edge_sum_kernel(const int* __restrict__ ei,
                                const float* __restrict__ als, const float* __restrict__ ald,
                                const unsigned* __restrict__ mx, float* __restrict__ ssum) {
  int e = blockIdx.x * blockDim.x + threadIdx.x;
  if (e >= NTOT) return;
  int s, d; edge_sd(ei, e, s, d);
#pragma unroll
  for (int h = 0; h < 4; ++h) {
    float v = als[s * 4 + h] + ald[d * 4 + h];
    v = v > 0.f ? v : 0.2f * v;
    atomicAdd(&ssum[d * 4 + h], expf(v - fdec(mx[d * 4 + h])));
  }
}

// ---- message aggregation: out[dst,c] += xp[src,c] * alpha(e,h) ----
__global__ __launch_bounds__(256) void edge_agg_kernel(
    const int* __restrict__ ei,
    const float* __restrict__ als, const float* __restrict__ ald,
    const unsigned* __restrict__ mx, const float* __restrict__ ssum,
    const float* __restrict__ xp, float* __restrict__ out) {
  int c = threadIdx.x;
  int h = c >> 6;
  for (int e = blockIdx.x; e < NTOT; e += gridDim.x) {
    int s, d; edge_sd(ei, e, s, d);
    float v = als[s * 4 + h] + ald[d * 4 + h];
    v = v > 0.f ? v : 0.2f * v;
    float coef = expf(v - fdec(mx[d * 4 + h])) / ssum[d * 4 + h];
    atomicAdd(&out[(size_t)d * HID + c], xp[(size_t)s * HID + c] * coef);
  }
}

__global__ void relu_bias_kernel(float* __restrict__ h, const float* __restrict__ bias, int total) {
  int idx = blockIdx.x * blockDim.x + threadIdx.x;
  if (idx >= total) return;
  float v = h[idx] + bias[idx & (HID - 1)];
  h[idx] = v > 0.f ? v : 0.f;
}

__global__ void pool_kernel(const float* __restrict__ h, const int* __restrict__ batch,
                            float* __restrict__ g) {
  int c = threadIdx.x;
  for (int r = blockIdx.x; r < NN; r += gridDim.x)
    atomicAdd(&g[(size_t)batch[r] * HID + c], h[(size_t)r * HID + c]);
}

// ---- small tail ops ----
__global__ void small_bn_kernel(const float* __restrict__ gin, const float* __restrict__ gamma,
                                const float* __restrict__ beta, float* __restrict__ gout, int rows) {
  int c = threadIdx.x; // 256
  float s = 0.f, ss = 0.f;
  for (int r = 0; r < rows; ++r) {
    float v = gin[r * HID + c];
    s += v; ss += v * v;
  }
  float m = s / rows, var = ss / rows - m * m;
  float sc = gamma[c] * rsqrtf(var + 1e-5f);
  float sh = beta[c] - m * sc;
  for (int r = 0; r < rows; ++r)
    gout[r * HID + c] = gin[r * HID + c] * sc + sh;
}

__global__ void small_fc_kernel(const float* __restrict__ gin, const float* __restrict__ W,
                                const float* __restrict__ b, float* __restrict__ gout) {
  __shared__ float row[HID];
  int gid = blockIdx.x, t = threadIdx.x;
  row[t] = gin[gid * HID + t];
  __syncthreads();
  float acc = b[t];
  for (int k = 0; k < HID; ++k) acc += row[k] * W[k * HID + t];
  gout[gid * HID + t] = acc > 0.f ? acc : 0.f;
}

__global__ void cls_kernel(const float* __restrict__ gin, const float* __restrict__ W,
                           const float* __restrict__ b, float* __restrict__ out) {
  __shared__ float row[HID];
  __shared__ float logits[NCLS];
  int g = blockIdx.x, t = threadIdx.x;
  row[t] = gin[g * HID + t];
  __syncthreads();
  if (t < NCLS) {
    float a = b[t];
    for (int k = 0; k < HID; ++k) a += row[k] * W[k * NCLS + t];
    logits[t] = a;
  }
  __syncthreads();
  if (t == 0) {
    float mxv = -1e30f;
    for (int i = 0; i < NCLS; ++i) mxv = fmaxf(mxv, logits[i]);
    float se = 0.f;
    for (int i = 0; i < NCLS; ++i) se += expf(logits[i] - mxv);
    float lse = mxv + logf(se);
    for (int i = 0; i < NCLS; ++i) out[g * NCLS + i] = logits[i] - lse;
  }
}

extern "C" void kernel_launch(void* const* d_in, const int* in_sizes, int n_in,
                              void* d_out, int out_size, void* d_ws, size_t ws_size,
                              hipStream_t stream) {
  const float* x        = (const float*)d_in[0];
  const int*   ei       = (const int*)d_in[1];
  const int*   batch    = (const int*)d_in[2];
  const float* bn_feat_g = (const float*)d_in[3];
  const float* bn_feat_b = (const float*)d_in[4];
  const float* W_feat   = (const float*)d_in[5];
  const float* b_feat   = (const float*)d_in[6];
  const float* bns_g    = (const float*)d_in[7];
  const float* bns_b    = (const float*)d_in[8];
  const float* Wg       = (const float*)d_in[9];
  const float* att_src  = (const float*)d_in[10];
  const float* att_dst  = (const float*)d_in[11];
  const float* gat_b    = (const float*)d_in[12];
  const float* bn_fc_g  = (const float*)d_in[13];
  const float* bn_fc_b  = (const float*)d_in[14];
  const float* W_fc     = (const float*)d_in[15];
  const float* b_fc     = (const float*)d_in[16];
  const float* bn_h_g   = (const float*)d_in[17];
  const float* bn_h_b   = (const float*)d_in[18];
  const float* W_cls    = (const float*)d_in[19];
  const float* b_cls    = (const float*)d_in[20];

  char* ws = (char*)d_ws;
  size_t off = 0;
  auto alloc = [&](size_t bytes) -> void* {
    void* p = ws + off;
    off += (bytes + 255) & ~(size_t)255;
    return p;
  };
  float*    sumw   = (float*)alloc(HID * 4);
  float*    sumsq  = (float*)alloc(HID * 4);
  float*    scale  = (float*)alloc(HID * 4);
  float*    shift  = (float*)alloc(HID * 4);
  float*    als    = (float*)alloc((size_t)NN * 4 * 4);
  float*    ald    = (float*)alloc((size_t)NN * 4 * 4);
  unsigned* mx     = (unsigned*)alloc((size_t)NN * 4 * 4);
  float*    ssum   = (float*)alloc((size_t)NN * 4 * 4);
  float*    bufA   = (float*)alloc((size_t)NN * HID * 4);  // h
  float*    bufB   = (float*)alloc((size_t)NN * HID * 4);  // xp
  float*    g0     = (float*)alloc((size_t)NG * HID * 4);
  float*    g1     = (float*)alloc((size_t)NG * HID * 4);
  (void)ws_size; (void)n_in; (void)in_sizes; (void)out_size;

  const int ETHREADS = 256;
  const int EGRID = (NTOT + ETHREADS - 1) / ETHREADS;

  // ---- stage 0: BN(x) folded into first GEMM, h1 = relu(BN(x)@W_feat + b_feat)
  hipMemsetAsync(sumw, 0, FIN * 4, stream);
  hipMemsetAsync(sumsq, 0, FIN * 4, stream);
  colstats_kernel<<<256, FIN, 0, stream>>>(x, NN, sumw, sumsq);
  finalize_stats<<<1, FIN, 0, stream>>>(sumw, sumsq, bn_feat_g, bn_feat_b,
                                        1.0f / NN, scale, shift);
  gemm_kernel<<<dim3((NN + 63) / 64, HID / 64), 256, 0, stream>>>(
      x, W_feat, scale, shift, b_feat, bufA, NN, FIN, HID, 1);

  // ---- 3 GAT layers
  for (int i = 0; i < 3; ++i) {
    hipMemsetAsync(sumw, 0, HID * 4, stream);
    hipMemsetAsync(sumsq, 0, HID * 4, stream);
    colstats_kernel<<<256, HID, 0, stream>>>(bufA, NN, sumw, sumsq);
    finalize_stats<<<1, HID, 0, stream>>>(sumw, sumsq, bns_g + i * HID, bns_b + i * HID,
                                          1.0f / NN, scale, shift);
    // xp = BN(h) @ Wg[i]
    gemm_kernel<<<dim3((NN + 63) / 64, HID / 64), 256, 0, stream>>>(
        bufA, Wg + (size_t)i * HID * HID, scale, shift, nullptr, bufB, NN, HID, HID, 0);
    attn_logits_kernel<<<(NN + 3) / 4, 256, 0, stream>>>(
        bufB, att_src + i * HID, att_dst + i * HID, als, ald);
    hipMemsetAsync(mx, 0, (size_t)NN * 16, stream);
    hipMemsetAsync(ssum, 0, (size_t)NN * 16, stream);
    edge_max_kernel<<<EGRID, ETHREADS, 0, stream>>>(ei, als, ald, mx);
    edge_sum_kernel<<<EGRID, ETHREADS, 0, stream>>>(ei, als, ald, mx, ssum);
    hipMemsetAsync(bufA, 0, (size_t)NN * HID * 4, stream);
    edge_agg_kernel<<<2048, 256, 0, stream>>>(ei, als, ald, mx, ssum, bufB, bufA);
    relu_bias_kernel<<<(NN * HID + 255) / 256, 256, 0, stream>>>(bufA, gat_b + i * HID, NN * HID);
  }

  // ---- pool + tail
  hipMemsetAsync(g0, 0, (size_t)NG * HID * 4, stream);
  pool_kernel<<<256, HID, 0, stream>>>(bufA, batch, g0);
  small_bn_kernel<<<1, HID, 0, stream>>>(g0, bn_fc_g, bn_fc_b, g1, NG);
  small_fc_kernel<<<NG, HID, 0, stream>>>(g1, W_fc, b_fc, g0);
  small_bn_kernel<<<1, HID, 0, stream>>>(g0, bn_h_g, bn_h_b, g1, NG);
  cls_kernel<<<NG, HID, 0, stream>>>(g1, W_cls, b_cls, (float*)d_out);
}

// Round 2
// 720.712 us; speedup vs baseline: 2.4157x; 2.4157x over previous
//
#include <hip/hip_runtime.h>

// Problem constants (fixed by reference)
constexpr int NN   = 20000;          // nodes
constexpr int NE   = 320000;         // edges (before self-loops)
constexpr int NTOT = NE + NN;        // edges incl self-loops
constexpr int FIN  = 128;
constexpr int HID  = 256;
constexpr int NG   = 128;            // graphs
constexpr int NCLS = 10;

// ---- per-column mean/var partials (blockDim.x == C) ----
__global__ void colstats_kernel(const float* __restrict__ X, int M,
                                float* __restrict__ sum, float* __restrict__ sumsq) {
  int C = blockDim.x;
  int c = threadIdx.x;
  float s = 0.f, ss = 0.f;
  for (int r = blockIdx.x; r < M; r += gridDim.x) {
    float v = X[(size_t)r * C + c];
    s += v; ss += v * v;
  }
  atomicAdd(&sum[c], s);
  atomicAdd(&sumsq[c], ss);
}

__global__ void finalize_stats(const float* __restrict__ sum, const float* __restrict__ sumsq,
                               const float* __restrict__ g, const float* __restrict__ b,
                               float invM, float* __restrict__ scale, float* __restrict__ shift) {
  int c = threadIdx.x;
  float m = sum[c] * invM;
  float v = sumsq[c] * invM - m * m;
  float sc = g[c] * rsqrtf(v + 1e-5f);
  scale[c] = sc;
  shift[c] = b[c] - m * sc;
}

// ---- f32 GEMM: C = [relu]( (A*scale+shift) @ B + bias ), tiles 64x64x16 ----
__global__ __launch_bounds__(256) void gemm_kernel(
    const float* __restrict__ A, const float* __restrict__ B,
    const float* __restrict__ scale, const float* __restrict__ shift,
    const float* __restrict__ bias, float* __restrict__ C,
    int M, int K, int N, int do_relu) {
  __shared__ float As[16][65];
  __shared__ float Bs[16][64];
  int tid = threadIdx.x;
  int tx = tid & 15, ty = tid >> 4;
  int bm = blockIdx.x * 64, bn = blockIdx.y * 64;
  int ar = tid >> 2, ak = (tid & 3) << 2;   // A tile: 64 rows x 16 k
  int bkr = tid >> 4, bno = (tid & 15) << 2; // B tile: 16 k x 64 n
  float acc[4][4] = {};
  for (int k0 = 0; k0 < K; k0 += 16) {
    float4 av = make_float4(0.f, 0.f, 0.f, 0.f);
    int arow = bm + ar;
    if (arow < M)
      av = *reinterpret_cast<const float4*>(A + (size_t)arow * K + k0 + ak);
    if (scale) {
      float4 sc = *reinterpret_cast<const float4*>(scale + k0 + ak);
      float4 sh = *reinterpret_cast<const float4*>(shift + k0 + ak);
      av.x = av.x * sc.x + sh.x;
      av.y = av.y * sc.y + sh.y;
      av.z = av.z * sc.z + sh.z;
      av.w = av.w * sc.w + sh.w;
    }
    As[ak + 0][ar] = av.x;
    As[ak + 1][ar] = av.y;
    As[ak + 2][ar] = av.z;
    As[ak + 3][ar] = av.w;
    float4 bv = *reinterpret_cast<const float4*>(B + (size_t)(k0 + bkr) * N + bn + bno);
    *reinterpret_cast<float4*>(&Bs[bkr][bno]) = bv;
    __syncthreads();
#pragma unroll
    for (int k = 0; k < 16; ++k) {
      float a[4], bb[4];
#pragma unroll
      for (int i = 0; i < 4; ++i) a[i] = As[k][ty * 4 + i];
#pragma unroll
      for (int j = 0; j < 4; ++j) bb[j] = Bs[k][tx * 4 + j];
#pragma unroll
      for (int i = 0; i < 4; ++i)
#pragma unroll
        for (int j = 0; j < 4; ++j) acc[i][j] += a[i] * bb[j];
    }
    __syncthreads();
  }
#pragma unroll
  for (int i = 0; i < 4; ++i) {
    int row = bm + ty * 4 + i;
    if (row >= M) continue;
#pragma unroll
    for (int j = 0; j < 4; ++j) {
      int col = bn + tx * 4 + j;
      float v = acc[i][j] + (bias ? bias[col] : 0.f);
      if (do_relu) v = fmaxf(v, 0.f);
      C[(size_t)row * N + col] = v;
    }
  }
}

// ---- per-node attention logits: als/ald [N,4], one wave per node ----
__global__ void attn_logits_kernel(const float* __restrict__ xp,
                                   const float* __restrict__ asrc,
                                   const float* __restrict__ adst,
                                   float* __restrict__ als, float* __restrict__ ald) {
  int wave = (blockIdx.x * blockDim.x + threadIdx.x) >> 6;
  int lane = threadIdx.x & 63;
  if (wave >= NN) return;
  const float* row = xp + (size_t)wave * HID;
#pragma unroll
  for (int h = 0; h < 4; ++h) {
    float v = row[h * 64 + lane];
    float s = v * asrc[h * 64 + lane];
    float d = v * adst[h * 64 + lane];
#pragma unroll
    for (int off = 32; off > 0; off >>= 1) {
      s += __shfl_down(s, off);
      d += __shfl_down(d, off);
    }
    if (lane == 0) {
      als[wave * 4 + h] = s;
      ald[wave * 4 + h] = d;
    }
  }
}

// ---- CSR build (dst is identical across all 3 layers; build once) ----
__device__ __forceinline__ void edge_sd(const int* __restrict__ ei, int e, int& s, int& d) {
  if (e < NE) { s = ei[e]; d = ei[NE + e]; }
  else        { s = e - NE; d = s; }
}

__global__ void zero_int_kernel(int* __restrict__ p, int n) {
  int i = blockIdx.x * blockDim.x + threadIdx.x;
  if (i < n) p[i] = 0;
}

__global__ void hist_kernel(const int* __restrict__ ei, int* __restrict__ deg) {
  int e = blockIdx.x * blockDim.x + threadIdx.x;
  if (e >= NTOT) return;
  int s, d; edge_sd(ei, e, s, d);
  atomicAdd(&deg[d], 1);
}

// single block, 1024 threads: exclusive scan of deg[NN] -> rp, cursor
__global__ __launch_bounds__(1024) void scan_kernel(const int* __restrict__ deg,
                                                    int* __restrict__ rp,
                                                    int* __restrict__ cursor) {
  __shared__ int part[1024];
  int t = threadIdx.x;
  const int C = (NN + 1023) / 1024;
  int base = t * C;
  int s = 0;
  for (int i = 0; i < C; ++i) {
    int idx = base + i;
    if (idx < NN) s += deg[idx];
  }
  part[t] = s;
  __syncthreads();
  for (int off = 1; off < 1024; off <<= 1) {
    int u = (t >= off) ? part[t - off] : 0;
    __syncthreads();
    part[t] += u;
    __syncthreads();
  }
  int run = part[t] - s;  // exclusive prefix of this thread's chunk
  for (int i = 0; i < C; ++i) {
    int idx = base + i;
    if (idx < NN) {
      rp[idx] = run;
      cursor[idx] = run;
      run += deg[idx];
    }
  }
  if (t == 1023) rp[NN] = part[1023];
}

__global__ void scatter_kernel(const int* __restrict__ ei, int* __restrict__ cursor,
                               int* __restrict__ col) {
  int e = blockIdx.x * blockDim.x + threadIdx.x;
  if (e >= NTOT) return;
  int s, d; edge_sd(ei, e, s, d);
  int pos = atomicAdd(&cursor[d], 1);
  col[pos] = s;
}

// ---- fused GAT aggregation: per dst node, softmax over in-edges + gather ----
constexpr int CHUNK = 128;
__global__ __launch_bounds__(256) void gat_agg_kernel(
    const int* __restrict__ rp, const int* __restrict__ col,
    const float* __restrict__ als, const float* __restrict__ ald,
    const float* __restrict__ xp, const float* __restrict__ bias,
    float* __restrict__ out) {
  __shared__ float s_m[4], s_is[4];
  __shared__ int s_src[CHUNK];
  __shared__ float s_coef[CHUNK * 4];
  int n = blockIdx.x;
  int beg = rp[n], deg = rp[n + 1] - beg;
  int tid = threadIdx.x, wave = tid >> 6, lane = tid & 63;
  float aldn = ald[n * 4 + wave];
  // pass 1: per-head max (wave w -> head w)
  float m = -1e30f;
  for (int j = lane; j < deg; j += 64) {
    int s = col[beg + j];
    float l = als[s * 4 + wave] + aldn;
    l = l > 0.f ? l : 0.2f * l;
    m = fmaxf(m, l);
  }
#pragma unroll
  for (int off = 32; off; off >>= 1) m = fmaxf(m, __shfl_xor(m, off));
  // pass 2: per-head sum of exp
  float ss = 0.f;
  for (int j = lane; j < deg; j += 64) {
    int s = col[beg + j];
    float l = als[s * 4 + wave] + aldn;
    l = l > 0.f ? l : 0.2f * l;
    ss += __expf(l - m);
  }
#pragma unroll
  for (int off = 32; off; off >>= 1) ss += __shfl_xor(ss, off);
  if (lane == 0) { s_m[wave] = m; s_is[wave] = 1.0f / ss; }
  // pass 3: chunked coef + channel accumulation
  int h = wave;
  int c = tid;
  float acc = 0.f;
  for (int j0 = 0; j0 < deg; j0 += CHUNK) {
    int cnt = min(CHUNK, deg - j0);
    __syncthreads();  // protects s_src/s_coef reuse AND covers s_m/s_is first time
    for (int j = tid; j < cnt; j += 256) s_src[j] = col[beg + j0 + j];
    __syncthreads();
    for (int idx = tid; idx < cnt * 4; idx += 256) {
      int j = idx >> 2, hh = idx & 3;
      int s = s_src[j];
      float l = als[s * 4 + hh] + ald[n * 4 + hh];
      l = l > 0.f ? l : 0.2f * l;
      s_coef[idx] = __expf(l - s_m[hh]) * s_is[hh];
    }
    __syncthreads();
    for (int j = 0; j < cnt; ++j)
      acc += s_coef[j * 4 + h] * xp[(size_t)s_src[j] * HID + c];
  }
  float v = acc + bias[c];
  out[(size_t)n * HID + c] = v > 0.f ? v : 0.f;
}

__global__ void pool_kernel(const float* __restrict__ h, const int* __restrict__ batch,
                            float* __restrict__ g) {
  int c = threadIdx.x;
  for (int r = blockIdx.x; r < NN; r += gridDim.x)
    atomicAdd(&g[(size_t)batch[r] * HID + c], h[(size_t)r * HID + c]);
}

// ---- small tail ops ----
__global__ void small_bn_kernel(const float* __restrict__ gin, const float* __restrict__ gamma,
                                const float* __restrict__ beta, float* __restrict__ gout, int rows) {
  int c = threadIdx.x; // 256
  float s = 0.f, ss = 0.f;
  for (int r = 0; r < rows; ++r) {
    float v = gin[r * HID + c];
    s += v; ss += v * v;
  }
  float m = s / rows, var = ss / rows - m * m;
  float sc = gamma[c] * rsqrtf(var + 1e-5f);
  float sh = beta[c] - m * sc;
  for (int r = 0; r < rows; ++r)
    gout[r * HID + c] = gin[r * HID + c] * sc + sh;
}

__global__ void small_fc_kernel(const float* __restrict__ gin, const float* __restrict__ W,
                                const float* __restrict__ b, float* __restrict__ gout) {
  __shared__ float row[HID];
  int gid = blockIdx.x, t = threadIdx.x;
  row[t] = gin[gid * HID + t];
  __syncthreads();
  float acc = b[t];
  for (int k = 0; k < HID; ++k) acc += row[k] * W[k * HID + t];
  gout[gid * HID + t] = acc > 0.f ? acc : 0.f;
}

__global__ void cls_kernel(const float* __restrict__ gin, const float* __restrict__ W,
                           const float* __restrict__ b, float* __restrict__ out) {
  __shared__ float row[HID];
  __shared__ float logits[NCLS];
  int g = blockIdx.x, t = threadIdx.x;
  row[t] = gin[g * HID + t];
  __syncthreads();
  if (t < NCLS) {
    float a = b[t];
    for (int k = 0; k < HID; ++k) a += row[k] * W[k * NCLS + t];
    logits[t] = a;
  }
  __syncthreads();
  if (t == 0) {
    float mxv = -1e30f;
    for (int i = 0; i < NCLS; ++i) mxv = fmaxf(mxv, logits[i]);
    float se = 0.f;
    for (int i = 0; i < NCLS; ++i) se += expf(logits[i] - mxv);
    float lse = mxv + logf(se);
    for (int i = 0; i < NCLS; ++i) out[g * NCLS + i] = logits[i] - lse;
  }
}

extern "C" void kernel_launch(void* const* d_in, const int* in_sizes, int n_in,
                              void* d_out, int out_size, void* d_ws, size_t ws_size,
                              hipStream_t stream) {
  const float* x        = (const float*)d_in[0];
  const int*   ei       = (const int*)d_in[1];
  const int*   batch    = (const int*)d_in[2];
  const float* bn_feat_g = (const float*)d_in[3];
  const float* bn_feat_b = (const float*)d_in[4];
  const float* W_feat   = (const float*)d_in[5];
  const float* b_feat   = (const float*)d_in[6];
  const float* bns_g    = (const float*)d_in[7];
  const float* bns_b    = (const float*)d_in[8];
  const float* Wg       = (const float*)d_in[9];
  const float* att_src  = (const float*)d_in[10];
  const float* att_dst  = (const float*)d_in[11];
  const float* gat_b    = (const float*)d_in[12];
  const float* bn_fc_g  = (const float*)d_in[13];
  const float* bn_fc_b  = (const float*)d_in[14];
  const float* W_fc     = (const float*)d_in[15];
  const float* b_fc     = (const float*)d_in[16];
  const float* bn_h_g   = (const float*)d_in[17];
  const float* bn_h_b   = (const float*)d_in[18];
  const float* W_cls    = (const float*)d_in[19];
  const float* b_cls    = (const float*)d_in[20];

  char* ws = (char*)d_ws;
  size_t off = 0;
  auto alloc = [&](size_t bytes) -> void* {
    void* p = ws + off;
    off += (bytes + 255) & ~(size_t)255;
    return p;
  };
  float* sumw   = (float*)alloc(HID * 4);
  float* sumsq  = (float*)alloc(HID * 4);
  float* scale  = (float*)alloc(HID * 4);
  float* shift  = (float*)alloc(HID * 4);
  float* als    = (float*)alloc((size_t)NN * 4 * 4);
  float* ald    = (float*)alloc((size_t)NN * 4 * 4);
  int*   deg    = (int*)alloc((size_t)NN * 4);
  int*   cursor = (int*)alloc((size_t)NN * 4);
  int*   rp     = (int*)alloc((size_t)(NN + 1) * 4);
  int*   col    = (int*)alloc((size_t)NTOT * 4);
  float* bufA   = (float*)alloc((size_t)NN * HID * 4);  // h
  float* bufB   = (float*)alloc((size_t)NN * HID * 4);  // xp
  float* g0     = (float*)alloc((size_t)NG * HID * 4);
  float* g1     = (float*)alloc((size_t)NG * HID * 4);
  (void)ws_size; (void)n_in; (void)in_sizes; (void)out_size;

  const int ETHREADS = 256;
  const int EGRID = (NTOT + ETHREADS - 1) / ETHREADS;

  // ---- CSR build (once; dst fixed across layers)
  zero_int_kernel<<<(NN + 255) / 256, 256, 0, stream>>>(deg, NN);
  hist_kernel<<<EGRID, ETHREADS, 0, stream>>>(ei, deg);
  scan_kernel<<<1, 1024, 0, stream>>>(deg, rp, cursor);
  scatter_kernel<<<EGRID, ETHREADS, 0, stream>>>(ei, cursor, col);

  // ---- stage 0: h = relu(BN(x) @ W_feat + b_feat)  (BN folded into GEMM)
  hipMemsetAsync(sumw, 0, FIN * 4, stream);
  hipMemsetAsync(sumsq, 0, FIN * 4, stream);
  colstats_kernel<<<256, FIN, 0, stream>>>(x, NN, sumw, sumsq);
  finalize_stats<<<1, FIN, 0, stream>>>(sumw, sumsq, bn_feat_g, bn_feat_b,
                                        1.0f / NN, scale, shift);
  gemm_kernel<<<dim3((NN + 63) / 64, HID / 64), 256, 0, stream>>>(
      x, W_feat, scale, shift, b_feat, bufA, NN, FIN, HID, 1);

  // ---- 3 GAT layers
  for (int i = 0; i < 3; ++i) {
    hipMemsetAsync(sumw, 0, HID * 4, stream);
    hipMemsetAsync(sumsq, 0, HID * 4, stream);
    colstats_kernel<<<256, HID, 0, stream>>>(bufA, NN, sumw, sumsq);
    finalize_stats<<<1, HID, 0, stream>>>(sumw, sumsq, bns_g + i * HID, bns_b + i * HID,
                                          1.0f / NN, scale, shift);
    // xp = BN(h) @ Wg[i]
    gemm_kernel<<<dim3((NN + 63) / 64, HID / 64), 256, 0, stream>>>(
        bufA, Wg + (size_t)i * HID * HID, scale, shift, nullptr, bufB, NN, HID, HID, 0);
    attn_logits_kernel<<<(NN + 3) / 4, 256, 0, stream>>>(
        bufB, att_src + i * HID, att_dst + i * HID, als, ald);
    // fused: dst-softmax + gather-aggregate + bias + relu
    gat_agg_kernel<<<NN, 256, 0, stream>>>(rp, col, als, ald, bufB,
                                           gat_b + i * HID, bufA);
  }

  // ---- pool + tail
  hipMemsetAsync(g0, 0, (size_t)NG * HID * 4, stream);
  pool_kernel<<<256, HID, 0, stream>>>(bufA, batch, g0);
  small_bn_kernel<<<1, HID, 0, stream>>>(g0, bn_fc_g, bn_fc_b, g1, NG);
  small_fc_kernel<<<NG, HID, 0, stream>>>(g1, W_fc, b_fc, g0);
  small_bn_kernel<<<1, HID, 0, stream>>>(g0, bn_h_g, bn_h_b, g1, NG);
  cls_kernel<<<NG, HID, 0, stream>>>(g1, W_cls, b_cls, (float*)d_out);
}

// Round 3
// 641.065 us; speedup vs baseline: 2.7159x; 1.1242x over previous
//
#include <hip/hip_runtime.h>

// Problem constants (fixed by reference)
constexpr int NN   = 20000;          // nodes
constexpr int NE   = 320000;         // edges (before self-loops)
constexpr int NTOT = NE + NN;        // edges incl self-loops
constexpr int FIN  = 128;
constexpr int HID  = 256;
constexpr int NG   = 128;            // graphs
constexpr int NCLS = 10;

typedef __bf16 bf16x8 __attribute__((ext_vector_type(8)));
typedef float  f32x4  __attribute__((ext_vector_type(4)));

__device__ __forceinline__ unsigned short f2b(float f) {
  unsigned u = __float_as_uint(f);
  unsigned r = (u + 0x7fffu + ((u >> 16) & 1u)) >> 16;
  return (unsigned short)r;
}
__device__ __forceinline__ float b2f(unsigned short h) {
  return __uint_as_float((unsigned)h << 16);
}

// ---- per-column mean/var partials (blockDim.x == C) ----
__global__ void colstats_kernel(const float* __restrict__ X, int M,
                                float* __restrict__ sum, float* __restrict__ sumsq) {
  int C = blockDim.x;
  int c = threadIdx.x;
  float s = 0.f, ss = 0.f;
  for (int r = blockIdx.x; r < M; r += gridDim.x) {
    float v = X[(size_t)r * C + c];
    s += v; ss += v * v;
  }
  atomicAdd(&sum[c], s);
  atomicAdd(&sumsq[c], ss);
}

__global__ void finalize_stats(const float* __restrict__ sum, const float* __restrict__ sumsq,
                               const float* __restrict__ g, const float* __restrict__ b,
                               float invM, float* __restrict__ scale, float* __restrict__ shift) {
  int c = threadIdx.x;
  float m = sum[c] * invM;
  float v = sumsq[c] * invM - m * m;
  float sc = g[c] * rsqrtf(v + 1e-5f);
  scale[c] = sc;
  shift[c] = b[c] - m * sc;
}

// ---- weight prep: W[K][256] f32 -> Wt[256][K] bf16 ----
__global__ void wprep_kernel(const float* __restrict__ W, unsigned short* __restrict__ Wt, int K) {
  int idx = blockIdx.x * 256 + threadIdx.x;
  if (idx >= K * 256) return;
  int k = idx >> 8, n = idx & 255;
  Wt[n * K + k] = f2b(W[idx]);
}

// ---- bf16 MFMA GEMM: C = [relu]( bf16(A*scale+shift) @ Wt^T + bias ) ----
// A: [M,K] f32, Wt: [N,K] bf16. Tiles 128x64x32, 4 waves (2x2).
__global__ __launch_bounds__(256) void gemm_mfma_kernel(
    const float* __restrict__ A, const unsigned short* __restrict__ Wt,
    const float* __restrict__ scale, const float* __restrict__ shift,
    const float* __restrict__ bias, float* __restrict__ Cf,
    unsigned short* __restrict__ Cb, int M, int K, int N, int do_relu) {
  __shared__ unsigned short Am[128][40];  // rows padded to 80B (16B aligned)
  __shared__ unsigned short Bn[64][40];
  int tid = threadIdx.x;
  int lane = tid & 63, wid = tid >> 6;
  int wm = wid >> 1, wn = wid & 1;
  int bm = blockIdx.x * 128, bn = blockIdx.y * 64;
  int lrow = lane & 15, lkh = (lane >> 4) * 8;

  int ar0 = tid >> 3;   // 0..31 (A row base, +32*i)
  int aks = tid & 7;    // 4-float segment in k
  int brow = tid >> 2;  // 0..63
  int bks = tid & 3;    // 8-bf16 segment in k

  f32x4 acc[4][2] = {};

  for (int k0 = 0; k0 < K; k0 += 32) {
#pragma unroll
    for (int i = 0; i < 4; ++i) {
      int r = ar0 + 32 * i;
      int grow = bm + r;
      float4 v = make_float4(0.f, 0.f, 0.f, 0.f);
      if (grow < M)
        v = *reinterpret_cast<const float4*>(A + (size_t)grow * K + k0 + aks * 4);
      if (scale) {
        float4 sc = *reinterpret_cast<const float4*>(scale + k0 + aks * 4);
        float4 sh = *reinterpret_cast<const float4*>(shift + k0 + aks * 4);
        v.x = v.x * sc.x + sh.x; v.y = v.y * sc.y + sh.y;
        v.z = v.z * sc.z + sh.z; v.w = v.w * sc.w + sh.w;
      }
      ushort4 p;
      p.x = f2b(v.x); p.y = f2b(v.y); p.z = f2b(v.z); p.w = f2b(v.w);
      *reinterpret_cast<ushort4*>(&Am[r][aks * 4]) = p;
    }
    {
      uint4 w = *reinterpret_cast<const uint4*>(Wt + (size_t)(bn + brow) * K + k0 + bks * 8);
      *reinterpret_cast<uint4*>(&Bn[brow][bks * 8]) = w;
    }
    __syncthreads();
    bf16x8 af[4], bfr[2];
#pragma unroll
    for (int i = 0; i < 4; ++i)
      af[i] = *reinterpret_cast<const bf16x8*>(&Am[wm * 64 + i * 16 + lrow][lkh]);
#pragma unroll
    for (int j = 0; j < 2; ++j)
      bfr[j] = *reinterpret_cast<const bf16x8*>(&Bn[wn * 32 + j * 16 + lrow][lkh]);
#pragma unroll
    for (int i = 0; i < 4; ++i)
#pragma unroll
      for (int j = 0; j < 2; ++j)
        acc[i][j] = __builtin_amdgcn_mfma_f32_16x16x32_bf16(af[i], bfr[j], acc[i][j], 0, 0, 0);
    __syncthreads();
  }

  int r4 = (lane >> 4) * 4;
#pragma unroll
  for (int i = 0; i < 4; ++i) {
#pragma unroll
    for (int j = 0; j < 2; ++j) {
#pragma unroll
      for (int r = 0; r < 4; ++r) {
        int row = bm + wm * 64 + i * 16 + r4 + r;
        int colv = bn + wn * 32 + j * 16 + lrow;
        if (row < M) {
          float v = acc[i][j][r] + (bias ? bias[colv] : 0.f);
          if (do_relu) v = fmaxf(v, 0.f);
          if (Cf) Cf[(size_t)row * N + colv] = v;
          else    Cb[(size_t)row * N + colv] = f2b(v);
        }
      }
    }
  }
}

// ---- per-node attention logits from bf16 xp: als/ald [N,4] ----
__global__ void attn_logits_kernel(const unsigned short* __restrict__ xp,
                                   const float* __restrict__ asrc,
                                   const float* __restrict__ adst,
                                   float* __restrict__ als, float* __restrict__ ald) {
  int wave = (blockIdx.x * blockDim.x + threadIdx.x) >> 6;
  int lane = threadIdx.x & 63;
  if (wave >= NN) return;
  const unsigned short* row = xp + (size_t)wave * HID;
#pragma unroll
  for (int h = 0; h < 4; ++h) {
    float v = b2f(row[h * 64 + lane]);
    float s = v * asrc[h * 64 + lane];
    float d = v * adst[h * 64 + lane];
#pragma unroll
    for (int off = 32; off > 0; off >>= 1) {
      s += __shfl_down(s, off);
      d += __shfl_down(d, off);
    }
    if (lane == 0) {
      als[wave * 4 + h] = s;
      ald[wave * 4 + h] = d;
    }
  }
}

// ---- CSR build (dst identical across layers; build once) ----
__device__ __forceinline__ void edge_sd(const int* __restrict__ ei, int e, int& s, int& d) {
  if (e < NE) { s = ei[e]; d = ei[NE + e]; }
  else        { s = e - NE; d = s; }
}

__global__ void zero_int_kernel(int* __restrict__ p, int n) {
  int i = blockIdx.x * blockDim.x + threadIdx.x;
  if (i < n) p[i] = 0;
}

__global__ void hist_kernel(const int* __restrict__ ei, int* __restrict__ deg) {
  int e = blockIdx.x * blockDim.x + threadIdx.x;
  if (e >= NTOT) return;
  int s, d; edge_sd(ei, e, s, d);
  atomicAdd(&deg[d], 1);
}

__global__ __launch_bounds__(1024) void scan_kernel(const int* __restrict__ deg,
                                                    int* __restrict__ rp,
                                                    int* __restrict__ cursor) {
  __shared__ int part[1024];
  int t = threadIdx.x;
  const int C = (NN + 1023) / 1024;
  int base = t * C;
  int s = 0;
  for (int i = 0; i < C; ++i) {
    int idx = base + i;
    if (idx < NN) s += deg[idx];
  }
  part[t] = s;
  __syncthreads();
  for (int off = 1; off < 1024; off <<= 1) {
    int u = (t >= off) ? part[t - off] : 0;
    __syncthreads();
    part[t] += u;
    __syncthreads();
  }
  int run = part[t] - s;
  for (int i = 0; i < C; ++i) {
    int idx = base + i;
    if (idx < NN) {
      rp[idx] = run;
      cursor[idx] = run;
      run += deg[idx];
    }
  }
  if (t == 1023) rp[NN] = part[1023];
}

__global__ void scatter_kernel(const int* __restrict__ ei, int* __restrict__ cursor,
                               int* __restrict__ col) {
  int e = blockIdx.x * blockDim.x + threadIdx.x;
  if (e >= NTOT) return;
  int s, d; edge_sd(ei, e, s, d);
  int pos = atomicAdd(&cursor[d], 1);
  col[pos] = s;
}

// ---- fused GAT aggregation: per dst node, softmax over in-edges + gather ----
constexpr int CHUNK = 128;
__global__ __launch_bounds__(256) void gat_agg_kernel(
    const int* __restrict__ rp, const int* __restrict__ col,
    const float* __restrict__ als, const float* __restrict__ ald,
    const unsigned short* __restrict__ xp, const float* __restrict__ bias,
    float* __restrict__ out) {
  __shared__ float s_m[4], s_is[4];
  __shared__ int s_src[CHUNK];
  __shared__ float s_coef[CHUNK * 4];
  int n = blockIdx.x;
  int beg = rp[n], deg = rp[n + 1] - beg;
  int tid = threadIdx.x, wave = tid >> 6, lane = tid & 63;
  float aldn = ald[n * 4 + wave];
  float m = -1e30f;
  for (int j = lane; j < deg; j += 64) {
    int s = col[beg + j];
    float l = als[s * 4 + wave] + aldn;
    l = l > 0.f ? l : 0.2f * l;
    m = fmaxf(m, l);
  }
#pragma unroll
  for (int off = 32; off; off >>= 1) m = fmaxf(m, __shfl_xor(m, off));
  float ss = 0.f;
  for (int j = lane; j < deg; j += 64) {
    int s = col[beg + j];
    float l = als[s * 4 + wave] + aldn;
    l = l > 0.f ? l : 0.2f * l;
    ss += __expf(l - m);
  }
#pragma unroll
  for (int off = 32; off; off >>= 1) ss += __shfl_xor(ss, off);
  if (lane == 0) { s_m[wave] = m; s_is[wave] = 1.0f / ss; }
  int h = wave;
  int c = tid;
  float acc = 0.f;
  for (int j0 = 0; j0 < deg; j0 += CHUNK) {
    int cnt = min(CHUNK, deg - j0);
    __syncthreads();
    for (int j = tid; j < cnt; j += 256) s_src[j] = col[beg + j0 + j];
    __syncthreads();
    for (int idx = tid; idx < cnt * 4; idx += 256) {
      int j = idx >> 2, hh = idx & 3;
      int s = s_src[j];
      float l = als[s * 4 + hh] + ald[n * 4 + hh];
      l = l > 0.f ? l : 0.2f * l;
      s_coef[idx] = __expf(l - s_m[hh]) * s_is[hh];
    }
    __syncthreads();
    for (int j = 0; j < cnt; ++j)
      acc += s_coef[j * 4 + h] * b2f(xp[(size_t)s_src[j] * HID + c]);
  }
  float v = acc + bias[c];
  out[(size_t)n * HID + c] = v > 0.f ? v : 0.f;
}

__global__ void pool_kernel(const float* __restrict__ h, const int* __restrict__ batch,
                            float* __restrict__ g) {
  int c = threadIdx.x;
  for (int r = blockIdx.x; r < NN; r += gridDim.x)
    atomicAdd(&g[(size_t)batch[r] * HID + c], h[(size_t)r * HID + c]);
}

// ---- small tail ops ----
__global__ void small_bn_kernel(const float* __restrict__ gin, const float* __restrict__ gamma,
                                const float* __restrict__ beta, float* __restrict__ gout, int rows) {
  int c = threadIdx.x;
  float s = 0.f, ss = 0.f;
  for (int r = 0; r < rows; ++r) {
    float v = gin[r * HID + c];
    s += v; ss += v * v;
  }
  float m = s / rows, var = ss / rows - m * m;
  float sc = gamma[c] * rsqrtf(var + 1e-5f);
  float sh = beta[c] - m * sc;
  for (int r = 0; r < rows; ++r)
    gout[r * HID + c] = gin[r * HID + c] * sc + sh;
}

__global__ void small_fc_kernel(const float* __restrict__ gin, const float* __restrict__ W,
                                const float* __restrict__ b, float* __restrict__ gout) {
  __shared__ float row[HID];
  int gid = blockIdx.x, t = threadIdx.x;
  row[t] = gin[gid * HID + t];
  __syncthreads();
  float acc = b[t];
  for (int k = 0; k < HID; ++k) acc += row[k] * W[k * HID + t];
  gout[gid * HID + t] = acc > 0.f ? acc : 0.f;
}

__global__ void cls_kernel(const float* __restrict__ gin, const float* __restrict__ W,
                           const float* __restrict__ b, float* __restrict__ out) {
  __shared__ float row[HID];
  __shared__ float logits[NCLS];
  int g = blockIdx.x, t = threadIdx.x;
  row[t] = gin[g * HID + t];
  __syncthreads();
  if (t < NCLS) {
    float a = b[t];
    for (int k = 0; k < HID; ++k) a += row[k] * W[k * NCLS + t];
    logits[t] = a;
  }
  __syncthreads();
  if (t == 0) {
    float mxv = -1e30f;
    for (int i = 0; i < NCLS; ++i) mxv = fmaxf(mxv, logits[i]);
    float se = 0.f;
    for (int i = 0; i < NCLS; ++i) se += expf(logits[i] - mxv);
    float lse = mxv + logf(se);
    for (int i = 0; i < NCLS; ++i) out[g * NCLS + i] = logits[i] - lse;
  }
}

extern "C" void kernel_launch(void* const* d_in, const int* in_sizes, int n_in,
                              void* d_out, int out_size, void* d_ws, size_t ws_size,
                              hipStream_t stream) {
  const float* x        = (const float*)d_in[0];
  const int*   ei       = (const int*)d_in[1];
  const int*   batch    = (const int*)d_in[2];
  const float* bn_feat_g = (const float*)d_in[3];
  const float* bn_feat_b = (const float*)d_in[4];
  const float* W_feat   = (const float*)d_in[5];
  const float* b_feat   = (const float*)d_in[6];
  const float* bns_g    = (const float*)d_in[7];
  const float* bns_b    = (const float*)d_in[8];
  const float* Wg       = (const float*)d_in[9];
  const float* att_src  = (const float*)d_in[10];
  const float* att_dst  = (const float*)d_in[11];
  const float* gat_b    = (const float*)d_in[12];
  const float* bn_fc_g  = (const float*)d_in[13];
  const float* bn_fc_b  = (const float*)d_in[14];
  const float* W_fc     = (const float*)d_in[15];
  const float* b_fc     = (const float*)d_in[16];
  const float* bn_h_g   = (const float*)d_in[17];
  const float* bn_h_b   = (const float*)d_in[18];
  const float* W_cls    = (const float*)d_in[19];
  const float* b_cls    = (const float*)d_in[20];

  char* ws = (char*)d_ws;
  size_t off = 0;
  auto alloc = [&](size_t bytes) -> void* {
    void* p = ws + off;
    off += (bytes + 255) & ~(size_t)255;
    return p;
  };
  float* sumw   = (float*)alloc(HID * 4);
  float* sumsq  = (float*)alloc(HID * 4);
  float* scale  = (float*)alloc(HID * 4);
  float* shift  = (float*)alloc(HID * 4);
  float* als    = (float*)alloc((size_t)NN * 4 * 4);
  float* ald    = (float*)alloc((size_t)NN * 4 * 4);
  int*   deg    = (int*)alloc((size_t)NN * 4);
  int*   cursor = (int*)alloc((size_t)NN * 4);
  int*   rp     = (int*)alloc((size_t)(NN + 1) * 4);
  int*   col    = (int*)alloc((size_t)NTOT * 4);
  unsigned short* Wft = (unsigned short*)alloc((size_t)HID * FIN * 2);
  unsigned short* Wgt = (unsigned short*)alloc((size_t)3 * HID * HID * 2);
  float* bufA   = (float*)alloc((size_t)NN * HID * 4);            // h (f32)
  unsigned short* xp = (unsigned short*)alloc((size_t)NN * HID * 2); // xp (bf16)
  float* g0     = (float*)alloc((size_t)NG * HID * 4);
  float* g1     = (float*)alloc((size_t)NG * HID * 4);
  (void)ws_size; (void)n_in; (void)in_sizes; (void)out_size;

  const int ETHREADS = 256;
  const int EGRID = (NTOT + ETHREADS - 1) / ETHREADS;

  // ---- CSR build + weight prep (independent of activations)
  zero_int_kernel<<<(NN + 255) / 256, 256, 0, stream>>>(deg, NN);
  hist_kernel<<<EGRID, ETHREADS, 0, stream>>>(ei, deg);
  scan_kernel<<<1, 1024, 0, stream>>>(deg, rp, cursor);
  scatter_kernel<<<EGRID, ETHREADS, 0, stream>>>(ei, cursor, col);
  wprep_kernel<<<(FIN * 256 + 255) / 256, 256, 0, stream>>>(W_feat, Wft, FIN);
  for (int i = 0; i < 3; ++i)
    wprep_kernel<<<(HID * 256 + 255) / 256, 256, 0, stream>>>(
        Wg + (size_t)i * HID * HID, Wgt + (size_t)i * HID * HID, HID);

  // ---- stage 0: h = relu(BN(x) @ W_feat + b_feat)
  hipMemsetAsync(sumw, 0, FIN * 4, stream);
  hipMemsetAsync(sumsq, 0, FIN * 4, stream);
  colstats_kernel<<<256, FIN, 0, stream>>>(x, NN, sumw, sumsq);
  finalize_stats<<<1, FIN, 0, stream>>>(sumw, sumsq, bn_feat_g, bn_feat_b,
                                        1.0f / NN, scale, shift);
  gemm_mfma_kernel<<<dim3((NN + 127) / 128, HID / 64), 256, 0, stream>>>(
      x, Wft, scale, shift, b_feat, bufA, nullptr, NN, FIN, HID, 1);

  // ---- 3 GAT layers
  for (int i = 0; i < 3; ++i) {
    hipMemsetAsync(sumw, 0, HID * 4, stream);
    hipMemsetAsync(sumsq, 0, HID * 4, stream);
    colstats_kernel<<<256, HID, 0, stream>>>(bufA, NN, sumw, sumsq);
    finalize_stats<<<1, HID, 0, stream>>>(sumw, sumsq, bns_g + i * HID, bns_b + i * HID,
                                          1.0f / NN, scale, shift);
    // xp = bf16( BN(h) @ Wg[i] )
    gemm_mfma_kernel<<<dim3((NN + 127) / 128, HID / 64), 256, 0, stream>>>(
        bufA, Wgt + (size_t)i * HID * HID, scale, shift, nullptr, nullptr, xp,
        NN, HID, HID, 0);
    attn_logits_kernel<<<(NN + 3) / 4, 256, 0, stream>>>(
        xp, att_src + i * HID, att_dst + i * HID, als, ald);
    gat_agg_kernel<<<NN, 256, 0, stream>>>(rp, col, als, ald, xp,
                                           gat_b + i * HID, bufA);
  }

  // ---- pool + tail
  hipMemsetAsync(g0, 0, (size_t)NG * HID * 4, stream);
  pool_kernel<<<256, HID, 0, stream>>>(bufA, batch, g0);
  small_bn_kernel<<<1, HID, 0, stream>>>(g0, bn_fc_g, bn_fc_b, g1, NG);
  small_fc_kernel<<<NG, HID, 0, stream>>>(g1, W_fc, b_fc, g0);
  small_bn_kernel<<<1, HID, 0, stream>>>(g0, bn_h_g, bn_h_b, g1, NG);
  cls_kernel<<<NG, HID, 0, stream>>>(g1, W_cls, b_cls, (float*)d_out);
}

// Round 4
// 619.956 us; speedup vs baseline: 2.8083x; 1.0340x over previous
//
#include <hip/hip_runtime.h>

// Problem constants (fixed by reference)
constexpr int NN   = 20000;          // nodes
constexpr int NE   = 320000;         // edges (before self-loops)
constexpr int NTOT = NE + NN;        // edges incl self-loops
constexpr int FIN  = 128;
constexpr int HID  = 256;
constexpr int NG   = 128;            // graphs
constexpr int NCLS = 10;

typedef __bf16 bf16x8 __attribute__((ext_vector_type(8)));
typedef float  f32x4  __attribute__((ext_vector_type(4)));

__device__ __forceinline__ unsigned short f2b(float f) {
  unsigned u = __float_as_uint(f);
  unsigned r = (u + 0x7fffu + ((u >> 16) & 1u)) >> 16;
  return (unsigned short)r;
}
__device__ __forceinline__ float b2f(unsigned short h) {
  return __uint_as_float((unsigned)h << 16);
}

// ---- per-column mean/var partials (grid MUST be 256 blocks; blockDim == C) ----
__global__ void colstats_f32_kernel(const float* __restrict__ X, int M,
                                    float* __restrict__ ps, float* __restrict__ pss) {
  int C = blockDim.x, c = threadIdx.x;
  float s = 0.f, ss = 0.f;
  for (int r = blockIdx.x; r < M; r += 256) {
    float v = X[(size_t)r * C + c];
    s += v; ss += v * v;
  }
  ps[blockIdx.x * 256 + c] = s;
  pss[blockIdx.x * 256 + c] = ss;
}

__global__ void colstats_bf16_kernel(const unsigned short* __restrict__ X, int M,
                                     float* __restrict__ ps, float* __restrict__ pss) {
  int C = blockDim.x, c = threadIdx.x;
  float s = 0.f, ss = 0.f;
  for (int r = blockIdx.x; r < M; r += 256) {
    float v = b2f(X[(size_t)r * C + c]);
    s += v; ss += v * v;
  }
  ps[blockIdx.x * 256 + c] = s;
  pss[blockIdx.x * 256 + c] = ss;
}

__global__ void finalize_stats(const float* __restrict__ ps, const float* __restrict__ pss,
                               const float* __restrict__ g, const float* __restrict__ b,
                               float invM, float* __restrict__ scale, float* __restrict__ shift) {
  int c = threadIdx.x;
  float s = 0.f, ss = 0.f;
  for (int k = 0; k < 256; ++k) { s += ps[k * 256 + c]; ss += pss[k * 256 + c]; }
  float m = s * invM;
  float v = ss * invM - m * m;
  float sc = g[c] * rsqrtf(v + 1e-5f);
  scale[c] = sc;
  shift[c] = b[c] - m * sc;
}

// ---- weight prep: W[K][256] f32 -> Wt[256][K] bf16 ----
__global__ void wprep_kernel(const float* __restrict__ W, unsigned short* __restrict__ Wt, int K) {
  int idx = blockIdx.x * 256 + threadIdx.x;
  if (idx >= K * 256) return;
  int k = idx >> 8, n = idx & 255;
  Wt[n * K + k] = f2b(W[idx]);
}

// ---- bf16 MFMA GEMM: C = [relu]( bf16(A*scale+shift) @ Wt^T + bias ) ----
// A: [M,K] f32 (Af) or bf16 (Ab); Wt: [N,K] bf16. Tiles 128x64x32, 4 waves (2x2).
__global__ __launch_bounds__(256) void gemm_mfma_kernel(
    const float* __restrict__ Af, const unsigned short* __restrict__ Ab,
    const unsigned short* __restrict__ Wt,
    const float* __restrict__ scale, const float* __restrict__ shift,
    const float* __restrict__ bias, float* __restrict__ Cf,
    unsigned short* __restrict__ Cb, int M, int K, int N, int do_relu) {
  __shared__ unsigned short Am[128][40];  // rows padded to 80B (16B aligned)
  __shared__ unsigned short Bn[64][40];
  int tid = threadIdx.x;
  int lane = tid & 63, wid = tid >> 6;
  int wm = wid >> 1, wn = wid & 1;
  int bm = blockIdx.x * 128, bn = blockIdx.y * 64;
  int lrow = lane & 15, lkh = (lane >> 4) * 8;

  int ar0 = tid >> 3;   // 0..31 (A row base, +32*i)
  int aks = tid & 7;    // 4-elem segment in k
  int brow = tid >> 2;  // 0..63
  int bks = tid & 3;    // 8-bf16 segment in k

  f32x4 acc[4][2] = {};

  for (int k0 = 0; k0 < K; k0 += 32) {
#pragma unroll
    for (int i = 0; i < 4; ++i) {
      int r = ar0 + 32 * i;
      int grow = bm + r;
      float4 v = make_float4(0.f, 0.f, 0.f, 0.f);
      if (grow < M) {
        if (Af) {
          v = *reinterpret_cast<const float4*>(Af + (size_t)grow * K + k0 + aks * 4);
        } else {
          ushort4 w = *reinterpret_cast<const ushort4*>(Ab + (size_t)grow * K + k0 + aks * 4);
          v.x = b2f(w.x); v.y = b2f(w.y); v.z = b2f(w.z); v.w = b2f(w.w);
        }
      }
      if (scale) {
        float4 sc = *reinterpret_cast<const float4*>(scale + k0 + aks * 4);
        float4 sh = *reinterpret_cast<const float4*>(shift + k0 + aks * 4);
        v.x = v.x * sc.x + sh.x; v.y = v.y * sc.y + sh.y;
        v.z = v.z * sc.z + sh.z; v.w = v.w * sc.w + sh.w;
      }
      ushort4 p;
      p.x = f2b(v.x); p.y = f2b(v.y); p.z = f2b(v.z); p.w = f2b(v.w);
      *reinterpret_cast<ushort4*>(&Am[r][aks * 4]) = p;
    }
    {
      uint4 w = *reinterpret_cast<const uint4*>(Wt + (size_t)(bn + brow) * K + k0 + bks * 8);
      *reinterpret_cast<uint4*>(&Bn[brow][bks * 8]) = w;
    }
    __syncthreads();
    bf16x8 af[4], bfr[2];
#pragma unroll
    for (int i = 0; i < 4; ++i)
      af[i] = *reinterpret_cast<const bf16x8*>(&Am[wm * 64 + i * 16 + lrow][lkh]);
#pragma unroll
    for (int j = 0; j < 2; ++j)
      bfr[j] = *reinterpret_cast<const bf16x8*>(&Bn[wn * 32 + j * 16 + lrow][lkh]);
#pragma unroll
    for (int i = 0; i < 4; ++i)
#pragma unroll
      for (int j = 0; j < 2; ++j)
        acc[i][j] = __builtin_amdgcn_mfma_f32_16x16x32_bf16(af[i], bfr[j], acc[i][j], 0, 0, 0);
    __syncthreads();
  }

  int r4 = (lane >> 4) * 4;
#pragma unroll
  for (int i = 0; i < 4; ++i) {
#pragma unroll
    for (int j = 0; j < 2; ++j) {
#pragma unroll
      for (int r = 0; r < 4; ++r) {
        int row = bm + wm * 64 + i * 16 + r4 + r;
        int colv = bn + wn * 32 + j * 16 + lrow;
        if (row < M) {
          float v = acc[i][j][r] + (bias ? bias[colv] : 0.f);
          if (do_relu) v = fmaxf(v, 0.f);
          if (Cf) Cf[(size_t)row * N + colv] = v;
          else    Cb[(size_t)row * N + colv] = f2b(v);
        }
      }
    }
  }
}

// ---- per-node attention logits: 4 nodes/block, vectorized ----
__global__ void attn_logits_kernel(const unsigned short* __restrict__ xp,
                                   const float* __restrict__ asrc,
                                   const float* __restrict__ adst,
                                   float* __restrict__ als, float* __restrict__ ald) {
  int node = blockIdx.x * 4 + (threadIdx.x >> 6);
  int lane = threadIdx.x & 63;
  if (node >= NN) return;
  int c0 = lane * 4;
  int h = lane >> 4;
  uint2 w = *reinterpret_cast<const uint2*>(xp + (size_t)node * HID + c0);
  float v0 = b2f((unsigned short)(w.x & 0xffff)), v1 = b2f((unsigned short)(w.x >> 16));
  float v2 = b2f((unsigned short)(w.y & 0xffff)), v3 = b2f((unsigned short)(w.y >> 16));
  float4 a = *reinterpret_cast<const float4*>(asrc + c0);
  float4 d = *reinterpret_cast<const float4*>(adst + c0);
  float s = v0 * a.x + v1 * a.y + v2 * a.z + v3 * a.w;
  float t = v0 * d.x + v1 * d.y + v2 * d.z + v3 * d.w;
#pragma unroll
  for (int off = 1; off < 16; off <<= 1) {
    s += __shfl_xor(s, off);
    t += __shfl_xor(t, off);
  }
  if ((lane & 15) == 0) {
    als[node * 4 + h] = s;
    ald[node * 4 + h] = t;
  }
}

// ---- CSR build (dst identical across layers; build once) ----
__device__ __forceinline__ void edge_sd(const int* __restrict__ ei, int e, int& s, int& d) {
  if (e < NE) { s = ei[e]; d = ei[NE + e]; }
  else        { s = e - NE; d = s; }
}

__global__ void zero_int_kernel(int* __restrict__ p, int n) {
  int i = blockIdx.x * blockDim.x + threadIdx.x;
  if (i < n) p[i] = 0;
}

__global__ void hist_kernel(const int* __restrict__ ei, int* __restrict__ deg) {
  int e = blockIdx.x * blockDim.x + threadIdx.x;
  if (e >= NTOT) return;
  int s, d; edge_sd(ei, e, s, d);
  atomicAdd(&deg[d], 1);
}

__global__ __launch_bounds__(1024) void scan_kernel(const int* __restrict__ deg,
                                                    int* __restrict__ rp,
                                                    int* __restrict__ cursor) {
  __shared__ int part[1024];
  int t = threadIdx.x;
  const int C = (NN + 1023) / 1024;
  int base = t * C;
  int s = 0;
  for (int i = 0; i < C; ++i) {
    int idx = base + i;
    if (idx < NN) s += deg[idx];
  }
  part[t] = s;
  __syncthreads();
  for (int off = 1; off < 1024; off <<= 1) {
    int u = (t >= off) ? part[t - off] : 0;
    __syncthreads();
    part[t] += u;
    __syncthreads();
  }
  int run = part[t] - s;
  for (int i = 0; i < C; ++i) {
    int idx = base + i;
    if (idx < NN) {
      rp[idx] = run;
      cursor[idx] = run;
      run += deg[idx];
    }
  }
  if (t == 1023) rp[NN] = part[1023];
}

__global__ void scatter_kernel(const int* __restrict__ ei, int* __restrict__ cursor,
                               int* __restrict__ col) {
  int e = blockIdx.x * blockDim.x + threadIdx.x;
  if (e >= NTOT) return;
  int s, d; edge_sd(ei, e, s, d);
  int pos = atomicAdd(&cursor[d], 1);
  col[pos] = s;
}

// ---- fused GAT aggregation: per dst node, online softmax + 4-way gather ----
constexpr int CHUNK = 128;
__global__ __launch_bounds__(256) void gat_agg_kernel(
    const int* __restrict__ rp, const int* __restrict__ col,
    const float* __restrict__ als, const float* __restrict__ ald,
    const unsigned short* __restrict__ xp, const float* __restrict__ bias,
    unsigned short* __restrict__ out) {
  __shared__ float s_mm[4], s_is[4];
  __shared__ int s_src[CHUNK];
  __shared__ float s_coef[CHUNK * 4];
  __shared__ float s_part[4][256];
  int n = blockIdx.x;
  int beg = rp[n], deg = rp[n + 1] - beg;
  int tid = threadIdx.x, wave = tid >> 6, lane = tid & 63;
  // online softmax stats; head == wave
  float aldn = ald[n * 4 + wave];
  float m = -1e30f, ssum = 0.f;
  for (int j = lane; j < deg; j += 64) {
    int s = col[beg + j];
    float l = als[s * 4 + wave] + aldn;
    l = l > 0.f ? l : 0.2f * l;
    float nm = fmaxf(m, l);
    ssum = ssum * __expf(m - nm) + __expf(l - nm);
    m = nm;
  }
#pragma unroll
  for (int off = 32; off; off >>= 1) {
    float om = __shfl_xor(m, off), os = __shfl_xor(ssum, off);
    float nm = fmaxf(m, om);
    ssum = ssum * __expf(m - nm) + os * __expf(om - nm);
    m = nm;
  }
  if (lane == 0) { s_mm[wave] = m; s_is[wave] = 1.0f / ssum; }
  // gather: wave g handles edges j % 4 == g; lane covers 4 channels
  int c0 = lane * 4;
  int h = lane >> 4;
  float a0 = 0.f, a1 = 0.f, a2 = 0.f, a3 = 0.f;
  for (int j0 = 0; j0 < deg; j0 += CHUNK) {
    int cnt = min(CHUNK, deg - j0);
    __syncthreads();  // also covers s_mm/s_is on first pass
    for (int j = tid; j < cnt; j += 256) s_src[j] = col[beg + j0 + j];
    __syncthreads();
    for (int idx = tid; idx < cnt * 4; idx += 256) {
      int j = idx >> 2, hh = idx & 3;
      int s = s_src[j];
      float l = als[s * 4 + hh] + ald[n * 4 + hh];
      l = l > 0.f ? l : 0.2f * l;
      s_coef[idx] = __expf(l - s_mm[hh]) * s_is[hh];
    }
    __syncthreads();
    for (int j = wave; j < cnt; j += 4) {
      int s = s_src[j];
      float cf = s_coef[j * 4 + h];
      uint2 w = *reinterpret_cast<const uint2*>(xp + (size_t)s * HID + c0);
      a0 += cf * b2f((unsigned short)(w.x & 0xffff));
      a1 += cf * b2f((unsigned short)(w.x >> 16));
      a2 += cf * b2f((unsigned short)(w.y & 0xffff));
      a3 += cf * b2f((unsigned short)(w.y >> 16));
    }
  }
  __syncthreads();
  *reinterpret_cast<float4*>(&s_part[wave][c0]) = make_float4(a0, a1, a2, a3);
  __syncthreads();
  int c = tid;
  float v = s_part[0][c] + s_part[1][c] + s_part[2][c] + s_part[3][c] + bias[c];
  v = v > 0.f ? v : 0.f;
  out[(size_t)n * HID + c] = f2b(v);
}

// ---- per-graph pool via binary search on sorted batch ----
__global__ void pool_kernel(const unsigned short* __restrict__ h, const int* __restrict__ batch,
                            float* __restrict__ g) {
  int gr = blockIdx.x, c = threadIdx.x;
  int lo = 0, hi = NN;
  while (lo < hi) { int mid = (lo + hi) >> 1; if (batch[mid] < gr) lo = mid + 1; else hi = mid; }
  int start = lo;
  hi = NN;
  while (lo < hi) { int mid = (lo + hi) >> 1; if (batch[mid] <= gr) lo = mid + 1; else hi = mid; }
  int end = lo;
  float s = 0.f;
  for (int r = start; r < end; ++r) s += b2f(h[(size_t)r * HID + c]);
  g[gr * HID + c] = s;
}

// ---- small tail ops ----
__global__ void small_bn_kernel(const float* __restrict__ gin, const float* __restrict__ gamma,
                                const float* __restrict__ beta, float* __restrict__ gout, int rows) {
  int c = threadIdx.x;
  float s = 0.f, ss = 0.f;
  for (int r = 0; r < rows; ++r) {
    float v = gin[r * HID + c];
    s += v; ss += v * v;
  }
  float m = s / rows, var = ss / rows - m * m;
  float sc = gamma[c] * rsqrtf(var + 1e-5f);
  float sh = beta[c] - m * sc;
  for (int r = 0; r < rows; ++r)
    gout[r * HID + c] = gin[r * HID + c] * sc + sh;
}

__global__ void small_fc_kernel(const float* __restrict__ gin, const float* __restrict__ W,
                                const float* __restrict__ b, float* __restrict__ gout) {
  __shared__ float row[HID];
  int gid = blockIdx.x, t = threadIdx.x;
  row[t] = gin[gid * HID + t];
  __syncthreads();
  float acc = b[t];
  for (int k = 0; k < HID; ++k) acc += row[k] * W[k * HID + t];
  gout[gid * HID + t] = acc > 0.f ? acc : 0.f;
}

__global__ void cls_kernel(const float* __restrict__ gin, const float* __restrict__ W,
                           const float* __restrict__ b, float* __restrict__ out) {
  __shared__ float row[HID];
  __shared__ float logits[NCLS];
  int g = blockIdx.x, t = threadIdx.x;
  row[t] = gin[g * HID + t];
  __syncthreads();
  if (t < NCLS) {
    float a = b[t];
    for (int k = 0; k < HID; ++k) a += row[k] * W[k * NCLS + t];
    logits[t] = a;
  }
  __syncthreads();
  if (t == 0) {
    float mxv = -1e30f;
    for (int i = 0; i < NCLS; ++i) mxv = fmaxf(mxv, logits[i]);
    float se = 0.f;
    for (int i = 0; i < NCLS; ++i) se += expf(logits[i] - mxv);
    float lse = mxv + logf(se);
    for (int i = 0; i < NCLS; ++i) out[g * NCLS + i] = logits[i] - lse;
  }
}

extern "C" void kernel_launch(void* const* d_in, const int* in_sizes, int n_in,
                              void* d_out, int out_size, void* d_ws, size_t ws_size,
                              hipStream_t stream) {
  const float* x        = (const float*)d_in[0];
  const int*   ei       = (const int*)d_in[1];
  const int*   batch    = (const int*)d_in[2];
  const float* bn_feat_g = (const float*)d_in[3];
  const float* bn_feat_b = (const float*)d_in[4];
  const float* W_feat   = (const float*)d_in[5];
  const float* b_feat   = (const float*)d_in[6];
  const float* bns_g    = (const float*)d_in[7];
  const float* bns_b    = (const float*)d_in[8];
  const float* Wg       = (const float*)d_in[9];
  const float* att_src  = (const float*)d_in[10];
  const float* att_dst  = (const float*)d_in[11];
  const float* gat_b    = (const float*)d_in[12];
  const float* bn_fc_g  = (const float*)d_in[13];
  const float* bn_fc_b  = (const float*)d_in[14];
  const float* W_fc     = (const float*)d_in[15];
  const float* b_fc     = (const float*)d_in[16];
  const float* bn_h_g   = (const float*)d_in[17];
  const float* bn_h_b   = (const float*)d_in[18];
  const float* W_cls    = (const float*)d_in[19];
  const float* b_cls    = (const float*)d_in[20];

  char* ws = (char*)d_ws;
  size_t off = 0;
  auto alloc = [&](size_t bytes) -> void* {
    void* p = ws + off;
    off += (bytes + 255) & ~(size_t)255;
    return p;
  };
  float* psum   = (float*)alloc(256 * 256 * 4);
  float* psumsq = (float*)alloc(256 * 256 * 4);
  float* scale  = (float*)alloc(HID * 4);
  float* shift  = (float*)alloc(HID * 4);
  float* als    = (float*)alloc((size_t)NN * 4 * 4);
  float* ald    = (float*)alloc((size_t)NN * 4 * 4);
  int*   deg    = (int*)alloc((size_t)NN * 4);
  int*   cursor = (int*)alloc((size_t)NN * 4);
  int*   rp     = (int*)alloc((size_t)(NN + 1) * 4);
  int*   col    = (int*)alloc((size_t)NTOT * 4);
  unsigned short* Wft = (unsigned short*)alloc((size_t)HID * FIN * 2);
  unsigned short* Wgt = (unsigned short*)alloc((size_t)3 * HID * HID * 2);
  unsigned short* bufA = (unsigned short*)alloc((size_t)NN * HID * 2);  // h (bf16)
  unsigned short* xp   = (unsigned short*)alloc((size_t)NN * HID * 2);  // xp (bf16)
  float* g0     = (float*)alloc((size_t)NG * HID * 4);
  float* g1     = (float*)alloc((size_t)NG * HID * 4);
  (void)ws_size; (void)n_in; (void)in_sizes; (void)out_size;

  const int ETHREADS = 256;
  const int EGRID = (NTOT + ETHREADS - 1) / ETHREADS;

  // ---- CSR build + weight prep (independent of activations)
  zero_int_kernel<<<(NN + 255) / 256, 256, 0, stream>>>(deg, NN);
  hist_kernel<<<EGRID, ETHREADS, 0, stream>>>(ei, deg);
  scan_kernel<<<1, 1024, 0, stream>>>(deg, rp, cursor);
  scatter_kernel<<<EGRID, ETHREADS, 0, stream>>>(ei, cursor, col);
  wprep_kernel<<<(FIN * 256 + 255) / 256, 256, 0, stream>>>(W_feat, Wft, FIN);
  for (int i = 0; i < 3; ++i)
    wprep_kernel<<<(HID * 256 + 255) / 256, 256, 0, stream>>>(
        Wg + (size_t)i * HID * HID, Wgt + (size_t)i * HID * HID, HID);

  // ---- stage 0: h = bf16(relu(BN(x) @ W_feat + b_feat))
  colstats_f32_kernel<<<256, FIN, 0, stream>>>(x, NN, psum, psumsq);
  finalize_stats<<<1, FIN, 0, stream>>>(psum, psumsq, bn_feat_g, bn_feat_b,
                                        1.0f / NN, scale, shift);
  gemm_mfma_kernel<<<dim3((NN + 127) / 128, HID / 64), 256, 0, stream>>>(
      x, nullptr, Wft, scale, shift, b_feat, nullptr, bufA, NN, FIN, HID, 1);

  // ---- 3 GAT layers
  for (int i = 0; i < 3; ++i) {
    colstats_bf16_kernel<<<256, HID, 0, stream>>>(bufA, NN, psum, psumsq);
    finalize_stats<<<1, HID, 0, stream>>>(psum, psumsq, bns_g + i * HID, bns_b + i * HID,
                                          1.0f / NN, scale, shift);
    // xp = bf16( BN(h) @ Wg[i] )
    gemm_mfma_kernel<<<dim3((NN + 127) / 128, HID / 64), 256, 0, stream>>>(
        nullptr, bufA, Wgt + (size_t)i * HID * HID, scale, shift, nullptr, nullptr, xp,
        NN, HID, HID, 0);
    attn_logits_kernel<<<(NN + 3) / 4, 256, 0, stream>>>(
        xp, att_src + i * HID, att_dst + i * HID, als, ald);
    gat_agg_kernel<<<NN, 256, 0, stream>>>(rp, col, als, ald, xp,
                                           gat_b + i * HID, bufA);
  }

  // ---- pool + tail
  pool_kernel<<<NG, HID, 0, stream>>>(bufA, batch, g0);
  small_bn_kernel<<<1, HID, 0, stream>>>(g0, bn_fc_g, bn_fc_b, g1, NG);
  small_fc_kernel<<<NG, HID, 0, stream>>>(g1, W_fc, b_fc, g0);
  small_bn_kernel<<<1, HID, 0, stream>>>(g0, bn_h_g, bn_h_b, g1, NG);
  cls_kernel<<<NG, HID, 0, stream>>>(g1, W_cls, b_cls, (float*)d_out);
}

// Round 5
// 521.726 us; speedup vs baseline: 3.3371x; 1.1883x over previous
//
#include <hip/hip_runtime.h>

// Problem constants (fixed by reference)
constexpr int NN   = 20000;          // nodes
constexpr int NE   = 320000;         // edges (before self-loops)
constexpr int NTOT = NE + NN;        // edges incl self-loops
constexpr int FIN  = 128;
constexpr int HID  = 256;
constexpr int NG   = 128;            // graphs
constexpr int NCLS = 10;

typedef __bf16 bf16x8 __attribute__((ext_vector_type(8)));
typedef float  f32x4  __attribute__((ext_vector_type(4)));

__device__ __forceinline__ unsigned short f2b(float f) {
  unsigned u = __float_as_uint(f);
  unsigned r = (u + 0x7fffu + ((u >> 16) & 1u)) >> 16;
  return (unsigned short)r;
}
__device__ __forceinline__ float b2f(unsigned short h) {
  return __uint_as_float((unsigned)h << 16);
}

// ---- per-column mean/var partials (grid MUST be 256 blocks; blockDim == C) ----
__global__ void colstats_f32_kernel(const float* __restrict__ X, int M,
                                    float* __restrict__ ps, float* __restrict__ pss) {
  int C = blockDim.x, c = threadIdx.x;
  float s = 0.f, ss = 0.f;
  for (int r = blockIdx.x; r < M; r += 256) {
    float v = X[(size_t)r * C + c];
    s += v; ss += v * v;
  }
  ps[blockIdx.x * 256 + c] = s;
  pss[blockIdx.x * 256 + c] = ss;
}

__global__ void colstats_bf16_kernel(const unsigned short* __restrict__ X, int M,
                                     float* __restrict__ ps, float* __restrict__ pss) {
  int C = blockDim.x, c = threadIdx.x;
  float s = 0.f, ss = 0.f;
  for (int r = blockIdx.x; r < M; r += 256) {
    float v = b2f(X[(size_t)r * C + c]);
    s += v; ss += v * v;
  }
  ps[blockIdx.x * 256 + c] = s;
  pss[blockIdx.x * 256 + c] = ss;
}

// one block per channel; 64 threads reduce the 256 partials
__global__ void finalize_stats(const float* __restrict__ ps, const float* __restrict__ pss,
                               const float* __restrict__ g, const float* __restrict__ b,
                               float invM, float* __restrict__ scale, float* __restrict__ shift) {
  int c = blockIdx.x, t = threadIdx.x;
  float s = 0.f, ss = 0.f;
#pragma unroll
  for (int k = 0; k < 4; ++k) {
    s  += ps[(t + k * 64) * 256 + c];
    ss += pss[(t + k * 64) * 256 + c];
  }
#pragma unroll
  for (int off = 32; off; off >>= 1) {
    s += __shfl_xor(s, off);
    ss += __shfl_xor(ss, off);
  }
  if (t == 0) {
    float m = s * invM;
    float v = ss * invM - m * m;
    float sc = g[c] * rsqrtf(v + 1e-5f);
    scale[c] = sc;
    shift[c] = b[c] - m * sc;
  }
}

// ---- weight prep: W[K][256] f32 -> Wt[256][K] bf16 ----
__global__ void wprep_kernel(const float* __restrict__ W, unsigned short* __restrict__ Wt, int K) {
  int idx = blockIdx.x * 256 + threadIdx.x;
  if (idx >= K * 256) return;
  int k = idx >> 8, n = idx & 255;
  Wt[n * K + k] = f2b(W[idx]);
}

// ---- bf16 MFMA GEMM: C = [relu]( bf16(A*scale+shift) @ Wt^T + bias ) ----
// A: [M,K] f32 (Af) or bf16 (Ab); Wt: [N,K] bf16. Tiles 128x64x32, 4 waves (2x2).
__global__ __launch_bounds__(256) void gemm_mfma_kernel(
    const float* __restrict__ Af, const unsigned short* __restrict__ Ab,
    const unsigned short* __restrict__ Wt,
    const float* __restrict__ scale, const float* __restrict__ shift,
    const float* __restrict__ bias, float* __restrict__ Cf,
    unsigned short* __restrict__ Cb, int M, int K, int N, int do_relu) {
  __shared__ unsigned short Am[128][40];  // rows padded to 80B (16B aligned)
  __shared__ unsigned short Bn[64][40];
  int tid = threadIdx.x;
  int lane = tid & 63, wid = tid >> 6;
  int wm = wid >> 1, wn = wid & 1;
  int bm = blockIdx.x * 128, bn = blockIdx.y * 64;
  int lrow = lane & 15, lkh = (lane >> 4) * 8;

  int ar0 = tid >> 3;   // 0..31 (A row base, +32*i)
  int aks = tid & 7;    // 4-elem segment in k
  int brow = tid >> 2;  // 0..63
  int bks = tid & 3;    // 8-bf16 segment in k

  f32x4 acc[4][2] = {};

  for (int k0 = 0; k0 < K; k0 += 32) {
#pragma unroll
    for (int i = 0; i < 4; ++i) {
      int r = ar0 + 32 * i;
      int grow = bm + r;
      float4 v = make_float4(0.f, 0.f, 0.f, 0.f);
      if (grow < M) {
        if (Af) {
          v = *reinterpret_cast<const float4*>(Af + (size_t)grow * K + k0 + aks * 4);
        } else {
          ushort4 w = *reinterpret_cast<const ushort4*>(Ab + (size_t)grow * K + k0 + aks * 4);
          v.x = b2f(w.x); v.y = b2f(w.y); v.z = b2f(w.z); v.w = b2f(w.w);
        }
      }
      if (scale) {
        float4 sc = *reinterpret_cast<const float4*>(scale + k0 + aks * 4);
        float4 sh = *reinterpret_cast<const float4*>(shift + k0 + aks * 4);
        v.x = v.x * sc.x + sh.x; v.y = v.y * sc.y + sh.y;
        v.z = v.z * sc.z + sh.z; v.w = v.w * sc.w + sh.w;
      }
      ushort4 p;
      p.x = f2b(v.x); p.y = f2b(v.y); p.z = f2b(v.z); p.w = f2b(v.w);
      *reinterpret_cast<ushort4*>(&Am[r][aks * 4]) = p;
    }
    {
      uint4 w = *reinterpret_cast<const uint4*>(Wt + (size_t)(bn + brow) * K + k0 + bks * 8);
      *reinterpret_cast<uint4*>(&Bn[brow][bks * 8]) = w;
    }
    __syncthreads();
    bf16x8 af[4], bfr[2];
#pragma unroll
    for (int i = 0; i < 4; ++i)
      af[i] = *reinterpret_cast<const bf16x8*>(&Am[wm * 64 + i * 16 + lrow][lkh]);
#pragma unroll
    for (int j = 0; j < 2; ++j)
      bfr[j] = *reinterpret_cast<const bf16x8*>(&Bn[wn * 32 + j * 16 + lrow][lkh]);
#pragma unroll
    for (int i = 0; i < 4; ++i)
#pragma unroll
      for (int j = 0; j < 2; ++j)
        acc[i][j] = __builtin_amdgcn_mfma_f32_16x16x32_bf16(af[i], bfr[j], acc[i][j], 0, 0, 0);
    __syncthreads();
  }

  int r4 = (lane >> 4) * 4;
#pragma unroll
  for (int i = 0; i < 4; ++i) {
#pragma unroll
    for (int j = 0; j < 2; ++j) {
#pragma unroll
      for (int r = 0; r < 4; ++r) {
        int row = bm + wm * 64 + i * 16 + r4 + r;
        int colv = bn + wn * 32 + j * 16 + lrow;
        if (row < M) {
          float v = acc[i][j][r] + (bias ? bias[colv] : 0.f);
          if (do_relu) v = fmaxf(v, 0.f);
          if (Cf) Cf[(size_t)row * N + colv] = v;
          else    Cb[(size_t)row * N + colv] = f2b(v);
        }
      }
    }
  }
}

// ---- per-node attention logits: 4 nodes/block, vectorized ----
__global__ void attn_logits_kernel(const unsigned short* __restrict__ xp,
                                   const float* __restrict__ asrc,
                                   const float* __restrict__ adst,
                                   float* __restrict__ als, float* __restrict__ ald) {
  int node = blockIdx.x * 4 + (threadIdx.x >> 6);
  int lane = threadIdx.x & 63;
  if (node >= NN) return;
  int c0 = lane * 4;
  int h = lane >> 4;
  uint2 w = *reinterpret_cast<const uint2*>(xp + (size_t)node * HID + c0);
  float v0 = b2f((unsigned short)(w.x & 0xffff)), v1 = b2f((unsigned short)(w.x >> 16));
  float v2 = b2f((unsigned short)(w.y & 0xffff)), v3 = b2f((unsigned short)(w.y >> 16));
  float4 a = *reinterpret_cast<const float4*>(asrc + c0);
  float4 d = *reinterpret_cast<const float4*>(adst + c0);
  float s = v0 * a.x + v1 * a.y + v2 * a.z + v3 * a.w;
  float t = v0 * d.x + v1 * d.y + v2 * d.z + v3 * d.w;
#pragma unroll
  for (int off = 1; off < 16; off <<= 1) {
    s += __shfl_xor(s, off);
    t += __shfl_xor(t, off);
  }
  if ((lane & 15) == 0) {
    als[node * 4 + h] = s;
    ald[node * 4 + h] = t;
  }
}

// ---- CSR build (dst identical across layers; build once) ----
__device__ __forceinline__ void edge_sd(const int* __restrict__ ei, int e, int& s, int& d) {
  if (e < NE) { s = ei[e]; d = ei[NE + e]; }
  else        { s = e - NE; d = s; }
}

__global__ void zero_int_kernel(int* __restrict__ p, int n) {
  int i = blockIdx.x * blockDim.x + threadIdx.x;
  if (i < n) p[i] = 0;
}

__global__ void hist_kernel(const int* __restrict__ ei, int* __restrict__ deg) {
  int e = blockIdx.x * blockDim.x + threadIdx.x;
  if (e >= NTOT) return;
  int s, d; edge_sd(ei, e, s, d);
  atomicAdd(&deg[d], 1);
}

__global__ __launch_bounds__(1024) void scan_kernel(const int* __restrict__ deg,
                                                    int* __restrict__ rp,
                                                    int* __restrict__ cursor) {
  __shared__ int part[1024];
  int t = threadIdx.x;
  const int C = (NN + 1023) / 1024;
  int base = t * C;
  int s = 0;
  for (int i = 0; i < C; ++i) {
    int idx = base + i;
    if (idx < NN) s += deg[idx];
  }
  part[t] = s;
  __syncthreads();
  for (int off = 1; off < 1024; off <<= 1) {
    int u = (t >= off) ? part[t - off] : 0;
    __syncthreads();
    part[t] += u;
    __syncthreads();
  }
  int run = part[t] - s;
  for (int i = 0; i < C; ++i) {
    int idx = base + i;
    if (idx < NN) {
      rp[idx] = run;
      cursor[idx] = run;
      run += deg[idx];
    }
  }
  if (t == 1023) rp[NN] = part[1023];
}

__global__ void scatter_kernel(const int* __restrict__ ei, int* __restrict__ cursor,
                               int* __restrict__ col) {
  int e = blockIdx.x * blockDim.x + threadIdx.x;
  if (e >= NTOT) return;
  int s, d; edge_sd(ei, e, s, d);
  int pos = atomicAdd(&cursor[d], 1);
  col[pos] = s;
}

// ---- fused GAT aggregation: ONE WAVE PER NODE (4 nodes/block, no LDS) ----
// Phase A: lanes (jof=lane>>2, hh=lane&3) do online softmax over edge subset.
// Butterfly (xor 4,8,16,32) merges lanes sharing a head.
// Phase B: computing lane makes coef; gather broadcasts src (shfl) and coef
// (bpermute); each lane accumulates its 4 channels from one coalesced uint2.
__global__ __launch_bounds__(256) void gat_agg_kernel(
    const int* __restrict__ rp, const int* __restrict__ col,
    const float* __restrict__ als, const float* __restrict__ ald,
    const unsigned short* __restrict__ xp, const float* __restrict__ bias,
    unsigned short* __restrict__ out) {
  int wv = threadIdx.x >> 6, lane = threadIdx.x & 63;
  int n = blockIdx.x * 4 + wv;
  if (n >= NN) return;
  int beg = rp[n], deg = rp[n + 1] - beg;
  int hh = lane & 3;       // head this lane computes logits for
  int jof = lane >> 2;     // edge offset within a 16-edge round
  float aldh = ald[n * 4 + hh];
  // phase A: per-lane online max/sum over its edges
  float m = -1e30f, ss = 0.f;
  for (int r0 = 0; r0 < deg; r0 += 16) {
    int j = r0 + jof;
    if (j < deg) {
      int s = col[beg + j];
      float l = als[s * 4 + hh] + aldh;
      l = l > 0.f ? l : 0.2f * l;
      float nm = fmaxf(m, l);
      ss = ss * __expf(m - nm) + __expf(l - nm);
      m = nm;
    }
  }
#pragma unroll
  for (int off = 4; off < 64; off <<= 1) {
    float om = __shfl_xor(m, off), os = __shfl_xor(ss, off);
    float nm = fmaxf(m, om);
    ss = ss * __expf(m - nm) + os * __expf(om - nm);
    m = nm;
  }
  float inv = 1.0f / ss;
  // phase B: coef + gather
  int c0 = lane * 4;       // this lane's 4 output channels
  int hme = lane >> 4;     // head of those channels
  float a0 = 0.f, a1 = 0.f, a2 = 0.f, a3 = 0.f;
  for (int r0 = 0; r0 < deg; r0 += 16) {
    int j = r0 + jof;
    int sreg = 0;
    float cf = 0.f;
    if (j < deg) {
      sreg = col[beg + j];
      float l = als[sreg * 4 + hh] + aldh;
      l = l > 0.f ? l : 0.2f * l;
      cf = __expf(l - m) * inv;
    }
    int cnt = min(16, deg - r0);
    for (int jj = 0; jj < cnt; ++jj) {
      int s = __shfl(sreg, jj << 2);
      float c = __shfl(cf, (jj << 2) | hme);
      uint2 w = *reinterpret_cast<const uint2*>(xp + (size_t)s * HID + c0);
      a0 += c * b2f((unsigned short)(w.x & 0xffff));
      a1 += c * b2f((unsigned short)(w.x >> 16));
      a2 += c * b2f((unsigned short)(w.y & 0xffff));
      a3 += c * b2f((unsigned short)(w.y >> 16));
    }
  }
  float4 bv = *reinterpret_cast<const float4*>(bias + c0);
  ushort4 o;
  o.x = f2b(fmaxf(a0 + bv.x, 0.f));
  o.y = f2b(fmaxf(a1 + bv.y, 0.f));
  o.z = f2b(fmaxf(a2 + bv.z, 0.f));
  o.w = f2b(fmaxf(a3 + bv.w, 0.f));
  *reinterpret_cast<ushort4*>(out + (size_t)n * HID + c0) = o;
}

// ---- pool: 256 blocks over contiguous node ranges, boundary atomics ----
__global__ void pool_kernel(const unsigned short* __restrict__ h, const int* __restrict__ batch,
                            float* __restrict__ g) {
  const int ROWS = (NN + 255) / 256;
  int r0 = blockIdx.x * ROWS;
  int r1 = min(r0 + ROWS, NN);
  if (r0 >= r1) return;
  int c = threadIdx.x;
  int cur = batch[r0];
  float acc = 0.f;
  for (int r = r0; r < r1; ++r) {
    int b = batch[r];
    if (b != cur) {
      atomicAdd(&g[(size_t)cur * HID + c], acc);
      acc = 0.f;
      cur = b;
    }
    acc += b2f(h[(size_t)r * HID + c]);
  }
  atomicAdd(&g[(size_t)cur * HID + c], acc);
}

// ---- small tail ops ----
__global__ void small_bn_kernel(const float* __restrict__ gin, const float* __restrict__ gamma,
                                const float* __restrict__ beta, float* __restrict__ gout, int rows) {
  int c = threadIdx.x;
  float s = 0.f, ss = 0.f;
  for (int r = 0; r < rows; ++r) {
    float v = gin[r * HID + c];
    s += v; ss += v * v;
  }
  float m = s / rows, var = ss / rows - m * m;
  float sc = gamma[c] * rsqrtf(var + 1e-5f);
  float sh = beta[c] - m * sc;
  for (int r = 0; r < rows; ++r)
    gout[r * HID + c] = gin[r * HID + c] * sc + sh;
}

__global__ void small_fc_kernel(const float* __restrict__ gin, const float* __restrict__ W,
                                const float* __restrict__ b, float* __restrict__ gout) {
  __shared__ float row[HID];
  int gid = blockIdx.x, t = threadIdx.x;
  row[t] = gin[gid * HID + t];
  __syncthreads();
  float acc = b[t];
  for (int k = 0; k < HID; ++k) acc += row[k] * W[k * HID + t];
  gout[gid * HID + t] = acc > 0.f ? acc : 0.f;
}

__global__ void cls_kernel(const float* __restrict__ gin, const float* __restrict__ W,
                           const float* __restrict__ b, float* __restrict__ out) {
  __shared__ float row[HID];
  __shared__ float logits[NCLS];
  int g = blockIdx.x, t = threadIdx.x;
  row[t] = gin[g * HID + t];
  __syncthreads();
  if (t < NCLS) {
    float a = b[t];
    for (int k = 0; k < HID; ++k) a += row[k] * W[k * NCLS + t];
    logits[t] = a;
  }
  __syncthreads();
  if (t == 0) {
    float mxv = -1e30f;
    for (int i = 0; i < NCLS; ++i) mxv = fmaxf(mxv, logits[i]);
    float se = 0.f;
    for (int i = 0; i < NCLS; ++i) se += expf(logits[i] - mxv);
    float lse = mxv + logf(se);
    for (int i = 0; i < NCLS; ++i) out[g * NCLS + i] = logits[i] - lse;
  }
}

extern "C" void kernel_launch(void* const* d_in, const int* in_sizes, int n_in,
                              void* d_out, int out_size, void* d_ws, size_t ws_size,
                              hipStream_t stream) {
  const float* x        = (const float*)d_in[0];
  const int*   ei       = (const int*)d_in[1];
  const int*   batch    = (const int*)d_in[2];
  const float* bn_feat_g = (const float*)d_in[3];
  const float* bn_feat_b = (const float*)d_in[4];
  const float* W_feat   = (const float*)d_in[5];
  const float* b_feat   = (const float*)d_in[6];
  const float* bns_g    = (const float*)d_in[7];
  const float* bns_b    = (const float*)d_in[8];
  const float* Wg       = (const float*)d_in[9];
  const float* att_src  = (const float*)d_in[10];
  const float* att_dst  = (const float*)d_in[11];
  const float* gat_b    = (const float*)d_in[12];
  const float* bn_fc_g  = (const float*)d_in[13];
  const float* bn_fc_b  = (const float*)d_in[14];
  const float* W_fc     = (const float*)d_in[15];
  const float* b_fc     = (const float*)d_in[16];
  const float* bn_h_g   = (const float*)d_in[17];
  const float* bn_h_b   = (const float*)d_in[18];
  const float* W_cls    = (const float*)d_in[19];
  const float* b_cls    = (const float*)d_in[20];

  char* ws = (char*)d_ws;
  size_t off = 0;
  auto alloc = [&](size_t bytes) -> void* {
    void* p = ws + off;
    off += (bytes + 255) & ~(size_t)255;
    return p;
  };
  float* psum   = (float*)alloc(256 * 256 * 4);
  float* psumsq = (float*)alloc(256 * 256 * 4);
  float* scale  = (float*)alloc(HID * 4);
  float* shift  = (float*)alloc(HID * 4);
  float* als    = (float*)alloc((size_t)NN * 4 * 4);
  float* ald    = (float*)alloc((size_t)NN * 4 * 4);
  int*   deg    = (int*)alloc((size_t)NN * 4);
  int*   cursor = (int*)alloc((size_t)NN * 4);
  int*   rp     = (int*)alloc((size_t)(NN + 1) * 4);
  int*   col    = (int*)alloc((size_t)NTOT * 4);
  unsigned short* Wft = (unsigned short*)alloc((size_t)HID * FIN * 2);
  unsigned short* Wgt = (unsigned short*)alloc((size_t)3 * HID * HID * 2);
  unsigned short* bufA = (unsigned short*)alloc((size_t)NN * HID * 2);  // h (bf16)
  unsigned short* xp   = (unsigned short*)alloc((size_t)NN * HID * 2);  // xp (bf16)
  float* g0     = (float*)alloc((size_t)NG * HID * 4);
  float* g1     = (float*)alloc((size_t)NG * HID * 4);
  (void)ws_size; (void)n_in; (void)in_sizes; (void)out_size;

  const int ETHREADS = 256;
  const int EGRID = (NTOT + ETHREADS - 1) / ETHREADS;

  // ---- CSR build + weight prep (independent of activations)
  zero_int_kernel<<<(NN + 255) / 256, 256, 0, stream>>>(deg, NN);
  hist_kernel<<<EGRID, ETHREADS, 0, stream>>>(ei, deg);
  scan_kernel<<<1, 1024, 0, stream>>>(deg, rp, cursor);
  scatter_kernel<<<EGRID, ETHREADS, 0, stream>>>(ei, cursor, col);
  wprep_kernel<<<(FIN * 256 + 255) / 256, 256, 0, stream>>>(W_feat, Wft, FIN);
  for (int i = 0; i < 3; ++i)
    wprep_kernel<<<(HID * 256 + 255) / 256, 256, 0, stream>>>(
        Wg + (size_t)i * HID * HID, Wgt + (size_t)i * HID * HID, HID);

  // ---- stage 0: h = bf16(relu(BN(x) @ W_feat + b_feat))
  colstats_f32_kernel<<<256, FIN, 0, stream>>>(x, NN, psum, psumsq);
  finalize_stats<<<FIN, 64, 0, stream>>>(psum, psumsq, bn_feat_g, bn_feat_b,
                                         1.0f / NN, scale, shift);
  gemm_mfma_kernel<<<dim3((NN + 127) / 128, HID / 64), 256, 0, stream>>>(
      x, nullptr, Wft, scale, shift, b_feat, nullptr, bufA, NN, FIN, HID, 1);

  // ---- 3 GAT layers
  for (int i = 0; i < 3; ++i) {
    colstats_bf16_kernel<<<256, HID, 0, stream>>>(bufA, NN, psum, psumsq);
    finalize_stats<<<HID, 64, 0, stream>>>(psum, psumsq, bns_g + i * HID, bns_b + i * HID,
                                           1.0f / NN, scale, shift);
    // xp = bf16( BN(h) @ Wg[i] )
    gemm_mfma_kernel<<<dim3((NN + 127) / 128, HID / 64), 256, 0, stream>>>(
        nullptr, bufA, Wgt + (size_t)i * HID * HID, scale, shift, nullptr, nullptr, xp,
        NN, HID, HID, 0);
    attn_logits_kernel<<<(NN + 3) / 4, 256, 0, stream>>>(
        xp, att_src + i * HID, att_dst + i * HID, als, ald);
    gat_agg_kernel<<<(NN + 3) / 4, 256, 0, stream>>>(rp, col, als, ald, xp,
                                                     gat_b + i * HID, bufA);
  }

  // ---- pool + tail
  hipMemsetAsync(g0, 0, (size_t)NG * HID * 4, stream);
  pool_kernel<<<256, HID, 0, stream>>>(bufA, batch, g0);
  small_bn_kernel<<<1, HID, 0, stream>>>(g0, bn_fc_g, bn_fc_b, g1, NG);
  small_fc_kernel<<<NG, HID, 0, stream>>>(g1, W_fc, b_fc, g0);
  small_bn_kernel<<<1, HID, 0, stream>>>(g0, bn_h_g, bn_h_b, g1, NG);
  cls_kernel<<<NG, HID, 0, stream>>>(g1, W_cls, b_cls, (float*)d_out);
}

// Round 6
// 420.411 us; speedup vs baseline: 4.1413x; 1.2410x over previous
//
#include <hip/hip_runtime.h>

// Problem constants (fixed by reference)
constexpr int NN   = 20000;          // nodes
constexpr int NE   = 320000;         // edges (before self-loops)
constexpr int NTOT = NE + NN;        // edges incl self-loops
constexpr int FIN  = 128;
constexpr int HID  = 256;
constexpr int NG   = 128;            // graphs
constexpr int NCLS = 10;

typedef __bf16 bf16x8 __attribute__((ext_vector_type(8)));
typedef float  f32x4  __attribute__((ext_vector_type(4)));

__device__ __forceinline__ unsigned short f2b(float f) {
  unsigned u = __float_as_uint(f);
  unsigned r = (u + 0x7fffu + ((u >> 16) & 1u)) >> 16;
  return (unsigned short)r;
}
__device__ __forceinline__ float b2f(unsigned short h) {
  return __uint_as_float((unsigned)h << 16);
}

// ---- x -> bf16 once ----
__global__ void xcast_kernel(const float* __restrict__ x, unsigned short* __restrict__ xb, int total4) {
  int i = blockIdx.x * blockDim.x + threadIdx.x;
  if (i >= total4) return;
  float4 v = *reinterpret_cast<const float4*>(x + (size_t)i * 4);
  ushort4 p;
  p.x = f2b(v.x); p.y = f2b(v.y); p.z = f2b(v.z); p.w = f2b(v.w);
  *reinterpret_cast<ushort4*>(xb + (size_t)i * 4) = p;
}

// ---- per-column mean/var partials (grid MUST be 256 blocks; blockDim == C) ----
__global__ void colstats_f32_kernel(const float* __restrict__ X, int M,
                                    float* __restrict__ ps, float* __restrict__ pss) {
  int C = blockDim.x, c = threadIdx.x;
  float s = 0.f, ss = 0.f;
  for (int r = blockIdx.x; r < M; r += 256) {
    float v = X[(size_t)r * C + c];
    s += v; ss += v * v;
  }
  ps[blockIdx.x * 256 + c] = s;
  pss[blockIdx.x * 256 + c] = ss;
}

__global__ void colstats_bf16_kernel(const unsigned short* __restrict__ X, int M,
                                     float* __restrict__ ps, float* __restrict__ pss) {
  int C = blockDim.x, c = threadIdx.x;
  float s = 0.f, ss = 0.f;
  for (int r = blockIdx.x; r < M; r += 256) {
    float v = b2f(X[(size_t)r * C + c]);
    s += v; ss += v * v;
  }
  ps[blockIdx.x * 256 + c] = s;
  pss[blockIdx.x * 256 + c] = ss;
}

// one block per channel; 64 threads reduce the 256 partials
__global__ void finalize_stats(const float* __restrict__ ps, const float* __restrict__ pss,
                               const float* __restrict__ g, const float* __restrict__ b,
                               float invM, float* __restrict__ scale, float* __restrict__ shift) {
  int c = blockIdx.x, t = threadIdx.x;
  float s = 0.f, ss = 0.f;
#pragma unroll
  for (int k = 0; k < 4; ++k) {
    s  += ps[(t + k * 64) * 256 + c];
    ss += pss[(t + k * 64) * 256 + c];
  }
#pragma unroll
  for (int off = 32; off; off >>= 1) {
    s += __shfl_xor(s, off);
    ss += __shfl_xor(ss, off);
  }
  if (t == 0) {
    float m = s * invM;
    float v = ss * invM - m * m;
    float sc = g[c] * rsqrtf(v + 1e-5f);
    scale[c] = sc;
    shift[c] = b[c] - m * sc;
  }
}

// ---- weight fold: Wt[n][k] = bf16(scale[k]*W[k][n]); bias2[n] = bias_in[n] + sum_k shift[k]*W[k][n]
__global__ __launch_bounds__(256) void wfold_kernel(const float* __restrict__ W,
    const float* __restrict__ scale, const float* __restrict__ shift,
    const float* __restrict__ bias_in, unsigned short* __restrict__ Wt,
    float* __restrict__ bias2, int K) {
  int n = blockIdx.x;   // 256
  int t = threadIdx.x;  // 256
  float part = 0.f;
  if (t < K) {
    float wv = W[(size_t)t * 256 + n];
    Wt[(size_t)n * K + t] = f2b(scale[t] * wv);
    part = shift[t] * wv;
  }
  __shared__ float red[256];
  red[t] = part;
  __syncthreads();
  if (t < 128) red[t] += red[t + 128];
  __syncthreads();
  if (t < 64) {
    float s = red[t] + red[t + 64];
#pragma unroll
    for (int off = 32; off; off >>= 1) s += __shfl_xor(s, off);
    if (t == 0) bias2[n] = (bias_in ? bias_in[n] : 0.f) + s;
  }
}

// ---- pure-bf16 MFMA GEMM: C = [relu]( A @ Wt^T + bias2 ), bf16 out ----
// A: [M,K] bf16, Wt: [256,K] bf16. Tiles 128x128x32, 4 waves (2x2), N fixed 256.
__global__ __launch_bounds__(256) void gemm_bf16_kernel(
    const unsigned short* __restrict__ Ab, const unsigned short* __restrict__ Wt,
    const float* __restrict__ bias2, unsigned short* __restrict__ Cb,
    int M, int K, int do_relu) {
  __shared__ unsigned short Am[128][40];  // rows padded to 80B (16B aligned, 2-way banks)
  __shared__ unsigned short Bn[128][40];
  int tid = threadIdx.x;
  int lane = tid & 63, wid = tid >> 6;
  int wm = wid >> 1, wn = wid & 1;
  int bm = blockIdx.x * 128, bn = blockIdx.y * 128;
  int lrow = lane & 15, lkh = (lane >> 4) * 8;
  int sr = tid >> 2;   // 0..63
  int ssg = tid & 3;   // 16B segment

  f32x4 acc[4][4] = {};

  for (int k0 = 0; k0 < K; k0 += 32) {
    {
      int ra = min(bm + sr, M - 1);
      uint4 v0 = *reinterpret_cast<const uint4*>(Ab + (size_t)ra * K + k0 + ssg * 8);
      *reinterpret_cast<uint4*>(&Am[sr][ssg * 8]) = v0;
      int rb = min(bm + sr + 64, M - 1);
      uint4 v1 = *reinterpret_cast<const uint4*>(Ab + (size_t)rb * K + k0 + ssg * 8);
      *reinterpret_cast<uint4*>(&Am[sr + 64][ssg * 8]) = v1;
      uint4 w0 = *reinterpret_cast<const uint4*>(Wt + (size_t)(bn + sr) * K + k0 + ssg * 8);
      *reinterpret_cast<uint4*>(&Bn[sr][ssg * 8]) = w0;
      uint4 w1 = *reinterpret_cast<const uint4*>(Wt + (size_t)(bn + sr + 64) * K + k0 + ssg * 8);
      *reinterpret_cast<uint4*>(&Bn[sr + 64][ssg * 8]) = w1;
    }
    __syncthreads();
    bf16x8 af[4], bfr[4];
#pragma unroll
    for (int i = 0; i < 4; ++i)
      af[i] = *reinterpret_cast<const bf16x8*>(&Am[wm * 64 + i * 16 + lrow][lkh]);
#pragma unroll
    for (int j = 0; j < 4; ++j)
      bfr[j] = *reinterpret_cast<const bf16x8*>(&Bn[wn * 64 + j * 16 + lrow][lkh]);
#pragma unroll
    for (int i = 0; i < 4; ++i)
#pragma unroll
      for (int j = 0; j < 4; ++j)
        acc[i][j] = __builtin_amdgcn_mfma_f32_16x16x32_bf16(af[i], bfr[j], acc[i][j], 0, 0, 0);
    __syncthreads();
  }

  int r4 = (lane >> 4) * 4;
#pragma unroll
  for (int i = 0; i < 4; ++i) {
#pragma unroll
    for (int j = 0; j < 4; ++j) {
      int colv = bn + wn * 64 + j * 16 + lrow;
      float bv = bias2[colv];
#pragma unroll
      for (int r = 0; r < 4; ++r) {
        int row = bm + wm * 64 + i * 16 + r4 + r;
        if (row < M) {
          float v = acc[i][j][r] + bv;
          if (do_relu) v = fmaxf(v, 0.f);
          Cb[(size_t)row * HID + colv] = f2b(v);
        }
      }
    }
  }
}

// ---- per-node attention logits: 4 nodes/block, vectorized ----
__global__ void attn_logits_kernel(const unsigned short* __restrict__ xp,
                                   const float* __restrict__ asrc,
                                   const float* __restrict__ adst,
                                   float* __restrict__ als, float* __restrict__ ald) {
  int node = blockIdx.x * 4 + (threadIdx.x >> 6);
  int lane = threadIdx.x & 63;
  if (node >= NN) return;
  int c0 = lane * 4;
  int h = lane >> 4;
  uint2 w = *reinterpret_cast<const uint2*>(xp + (size_t)node * HID + c0);
  float v0 = b2f((unsigned short)(w.x & 0xffff)), v1 = b2f((unsigned short)(w.x >> 16));
  float v2 = b2f((unsigned short)(w.y & 0xffff)), v3 = b2f((unsigned short)(w.y >> 16));
  float4 a = *reinterpret_cast<const float4*>(asrc + c0);
  float4 d = *reinterpret_cast<const float4*>(adst + c0);
  float s = v0 * a.x + v1 * a.y + v2 * a.z + v3 * a.w;
  float t = v0 * d.x + v1 * d.y + v2 * d.z + v3 * d.w;
#pragma unroll
  for (int off = 1; off < 16; off <<= 1) {
    s += __shfl_xor(s, off);
    t += __shfl_xor(t, off);
  }
  if ((lane & 15) == 0) {
    als[node * 4 + h] = s;
    ald[node * 4 + h] = t;
  }
}

// ---- CSR build (dst identical across layers; build once) ----
__device__ __forceinline__ void edge_sd(const int* __restrict__ ei, int e, int& s, int& d) {
  if (e < NE) { s = ei[e]; d = ei[NE + e]; }
  else        { s = e - NE; d = s; }
}

__global__ void zero_int_kernel(int* __restrict__ p, int n) {
  int i = blockIdx.x * blockDim.x + threadIdx.x;
  if (i < n) p[i] = 0;
}

__global__ void hist_kernel(const int* __restrict__ ei, int* __restrict__ deg) {
  int e = blockIdx.x * blockDim.x + threadIdx.x;
  if (e >= NTOT) return;
  int s, d; edge_sd(ei, e, s, d);
  atomicAdd(&deg[d], 1);
}

__global__ __launch_bounds__(1024) void scan_kernel(const int* __restrict__ deg,
                                                    int* __restrict__ rp,
                                                    int* __restrict__ cursor) {
  __shared__ int part[1024];
  int t = threadIdx.x;
  const int C = (NN + 1023) / 1024;
  int base = t * C;
  int s = 0;
  for (int i = 0; i < C; ++i) {
    int idx = base + i;
    if (idx < NN) s += deg[idx];
  }
  part[t] = s;
  __syncthreads();
  for (int off = 1; off < 1024; off <<= 1) {
    int u = (t >= off) ? part[t - off] : 0;
    __syncthreads();
    part[t] += u;
    __syncthreads();
  }
  int run = part[t] - s;
  for (int i = 0; i < C; ++i) {
    int idx = base + i;
    if (idx < NN) {
      rp[idx] = run;
      cursor[idx] = run;
      run += deg[idx];
    }
  }
  if (t == 1023) rp[NN] = part[1023];
}

__global__ void scatter_kernel(const int* __restrict__ ei, int* __restrict__ cursor,
                               int* __restrict__ col) {
  int e = blockIdx.x * blockDim.x + threadIdx.x;
  if (e >= NTOT) return;
  int s, d; edge_sd(ei, e, s, d);
  int pos = atomicAdd(&cursor[d], 1);
  col[pos] = s;
}

// ---- fused GAT aggregation: ONE WAVE PER NODE, single-exp ----
// Phase A: max only. Phase B: exp once, unnormalized gather + ssum in parallel.
// Final: butterfly ssum, normalize at the end.
__global__ __launch_bounds__(256) void gat_agg_kernel(
    const int* __restrict__ rp, const int* __restrict__ col,
    const float* __restrict__ als, const float* __restrict__ ald,
    const unsigned short* __restrict__ xp, const float* __restrict__ bias,
    unsigned short* __restrict__ out) {
  int wv = threadIdx.x >> 6, lane = threadIdx.x & 63;
  int n = blockIdx.x * 4 + wv;
  if (n >= NN) return;
  int beg = rp[n], deg = rp[n + 1] - beg;
  int hh = lane & 3;       // head this lane computes logits for
  int jof = lane >> 2;     // edge offset within a 16-edge round
  float aldh = ald[n * 4 + hh];
  // phase A: global max per head
  float m = -1e30f;
  for (int r0 = 0; r0 < deg; r0 += 16) {
    int j = r0 + jof;
    if (j < deg) {
      int s = col[beg + j];
      float l = als[s * 4 + hh] + aldh;
      l = l > 0.f ? l : 0.2f * l;
      m = fmaxf(m, l);
    }
  }
#pragma unroll
  for (int off = 4; off < 64; off <<= 1) m = fmaxf(m, __shfl_xor(m, off));
  // phase B: exp + unnormalized gather + ssum
  int c0 = lane * 4;       // this lane's 4 output channels
  int hme = lane >> 4;     // head of those channels
  float ss = 0.f;
  float a0 = 0.f, a1 = 0.f, a2 = 0.f, a3 = 0.f;
  for (int r0 = 0; r0 < deg; r0 += 16) {
    int j = r0 + jof;
    int sreg = 0;
    float cf = 0.f;
    if (j < deg) {
      sreg = col[beg + j];
      float l = als[sreg * 4 + hh] + aldh;
      l = l > 0.f ? l : 0.2f * l;
      cf = __expf(l - m);
      ss += cf;
    }
    int cnt = min(16, deg - r0);
    for (int jj = 0; jj < cnt; ++jj) {
      int s = __shfl(sreg, jj << 2);
      float c = __shfl(cf, (jj << 2) | hme);
      uint2 w = *reinterpret_cast<const uint2*>(xp + (size_t)s * HID + c0);
      a0 += c * b2f((unsigned short)(w.x & 0xffff));
      a1 += c * b2f((unsigned short)(w.x >> 16));
      a2 += c * b2f((unsigned short)(w.y & 0xffff));
      a3 += c * b2f((unsigned short)(w.y >> 16));
    }
  }
#pragma unroll
  for (int off = 4; off < 64; off <<= 1) ss += __shfl_xor(ss, off);
  float inv = 1.0f / __shfl(ss, hme);   // lane hme holds the total for head hme
  float4 bv = *reinterpret_cast<const float4*>(bias + c0);
  ushort4 o;
  o.x = f2b(fmaxf(a0 * inv + bv.x, 0.f));
  o.y = f2b(fmaxf(a1 * inv + bv.y, 0.f));
  o.z = f2b(fmaxf(a2 * inv + bv.z, 0.f));
  o.w = f2b(fmaxf(a3 * inv + bv.w, 0.f));
  *reinterpret_cast<ushort4*>(out + (size_t)n * HID + c0) = o;
}

// ---- pool: 256 blocks over contiguous node ranges, boundary atomics ----
__global__ void pool_kernel(const unsigned short* __restrict__ h, const int* __restrict__ batch,
                            float* __restrict__ g) {
  const int ROWS = (NN + 255) / 256;
  int r0 = blockIdx.x * ROWS;
  int r1 = min(r0 + ROWS, NN);
  if (r0 >= r1) return;
  int c = threadIdx.x;
  int cur = batch[r0];
  float acc = 0.f;
  for (int r = r0; r < r1; ++r) {
    int b = batch[r];
    if (b != cur) {
      atomicAdd(&g[(size_t)cur * HID + c], acc);
      acc = 0.f;
      cur = b;
    }
    acc += b2f(h[(size_t)r * HID + c]);
  }
  atomicAdd(&g[(size_t)cur * HID + c], acc);
}

// ---- small tail ops ----
// one block per channel; 128 threads = 128 rows
__global__ void small_bn_kernel(const float* __restrict__ gin, const float* __restrict__ gamma,
                                const float* __restrict__ beta, float* __restrict__ gout) {
  int c = blockIdx.x, t = threadIdx.x;  // t < NG
  float v = gin[(size_t)t * HID + c];
  float s = v, ss = v * v;
#pragma unroll
  for (int off = 32; off; off >>= 1) {
    s += __shfl_xor(s, off);
    ss += __shfl_xor(ss, off);
  }
  __shared__ float sm[2], ssm[2];
  if ((t & 63) == 0) { sm[t >> 6] = s; ssm[t >> 6] = ss; }
  __syncthreads();
  float S = sm[0] + sm[1], SS = ssm[0] + ssm[1];
  float mn = S / NG, var = SS / NG - mn * mn;
  float sc = gamma[c] * rsqrtf(var + 1e-5f);
  float sh = beta[c] - mn * sc;
  gout[(size_t)t * HID + c] = v * sc + sh;
}

__global__ void small_fc_kernel(const float* __restrict__ gin, const float* __restrict__ W,
                                const float* __restrict__ b, float* __restrict__ gout) {
  __shared__ float row[HID];
  int gid = blockIdx.x, t = threadIdx.x;
  row[t] = gin[gid * HID + t];
  __syncthreads();
  float acc = b[t];
  for (int k = 0; k < HID; ++k) acc += row[k] * W[k * HID + t];
  gout[gid * HID + t] = acc > 0.f ? acc : 0.f;
}

__global__ void cls_kernel(const float* __restrict__ gin, const float* __restrict__ W,
                           const float* __restrict__ b, float* __restrict__ out) {
  __shared__ float row[HID];
  __shared__ float logits[NCLS];
  int g = blockIdx.x, t = threadIdx.x;
  row[t] = gin[g * HID + t];
  __syncthreads();
  if (t < NCLS) {
    float a = b[t];
    for (int k = 0; k < HID; ++k) a += row[k] * W[k * NCLS + t];
    logits[t] = a;
  }
  __syncthreads();
  if (t == 0) {
    float mxv = -1e30f;
    for (int i = 0; i < NCLS; ++i) mxv = fmaxf(mxv, logits[i]);
    float se = 0.f;
    for (int i = 0; i < NCLS; ++i) se += expf(logits[i] - mxv);
    float lse = mxv + logf(se);
    for (int i = 0; i < NCLS; ++i) out[g * NCLS + i] = logits[i] - lse;
  }
}

extern "C" void kernel_launch(void* const* d_in, const int* in_sizes, int n_in,
                              void* d_out, int out_size, void* d_ws, size_t ws_size,
                              hipStream_t stream) {
  const float* x        = (const float*)d_in[0];
  const int*   ei       = (const int*)d_in[1];
  const int*   batch    = (const int*)d_in[2];
  const float* bn_feat_g = (const float*)d_in[3];
  const float* bn_feat_b = (const float*)d_in[4];
  const float* W_feat   = (const float*)d_in[5];
  const float* b_feat   = (const float*)d_in[6];
  const float* bns_g    = (const float*)d_in[7];
  const float* bns_b    = (const float*)d_in[8];
  const float* Wg       = (const float*)d_in[9];
  const float* att_src  = (const float*)d_in[10];
  const float* att_dst  = (const float*)d_in[11];
  const float* gat_b    = (const float*)d_in[12];
  const float* bn_fc_g  = (const float*)d_in[13];
  const float* bn_fc_b  = (const float*)d_in[14];
  const float* W_fc     = (const float*)d_in[15];
  const float* b_fc     = (const float*)d_in[16];
  const float* bn_h_g   = (const float*)d_in[17];
  const float* bn_h_b   = (const float*)d_in[18];
  const float* W_cls    = (const float*)d_in[19];
  const float* b_cls    = (const float*)d_in[20];

  char* ws = (char*)d_ws;
  size_t off = 0;
  auto alloc = [&](size_t bytes) -> void* {
    void* p = ws + off;
    off += (bytes + 255) & ~(size_t)255;
    return p;
  };
  float* psum   = (float*)alloc(256 * 256 * 4);
  float* psumsq = (float*)alloc(256 * 256 * 4);
  float* scale  = (float*)alloc(HID * 4);
  float* shift  = (float*)alloc(HID * 4);
  float* bias2  = (float*)alloc(HID * 4);
  float* als    = (float*)alloc((size_t)NN * 4 * 4);
  float* ald    = (float*)alloc((size_t)NN * 4 * 4);
  int*   deg    = (int*)alloc((size_t)NN * 4);
  int*   cursor = (int*)alloc((size_t)NN * 4);
  int*   rp     = (int*)alloc((size_t)(NN + 1) * 4);
  int*   col    = (int*)alloc((size_t)NTOT * 4);
  unsigned short* xb  = (unsigned short*)alloc((size_t)NN * FIN * 2);   // x bf16
  unsigned short* Wft = (unsigned short*)alloc((size_t)HID * FIN * 2);  // folded stage0 W
  unsigned short* Wgt = (unsigned short*)alloc((size_t)HID * HID * 2);  // folded layer W (reused)
  unsigned short* bufA = (unsigned short*)alloc((size_t)NN * HID * 2);  // h (bf16)
  unsigned short* xp   = (unsigned short*)alloc((size_t)NN * HID * 2);  // xp (bf16)
  float* g0     = (float*)alloc((size_t)NG * HID * 4);
  float* g1     = (float*)alloc((size_t)NG * HID * 4);
  (void)ws_size; (void)n_in; (void)in_sizes; (void)out_size;

  const int ETHREADS = 256;
  const int EGRID = (NTOT + ETHREADS - 1) / ETHREADS;

  // ---- CSR build + x cast (independent of activations)
  zero_int_kernel<<<(NN + 255) / 256, 256, 0, stream>>>(deg, NN);
  hist_kernel<<<EGRID, ETHREADS, 0, stream>>>(ei, deg);
  scan_kernel<<<1, 1024, 0, stream>>>(deg, rp, cursor);
  scatter_kernel<<<EGRID, ETHREADS, 0, stream>>>(ei, cursor, col);
  xcast_kernel<<<(NN * FIN / 4 + 255) / 256, 256, 0, stream>>>(x, xb, NN * FIN / 4);

  // ---- stage 0: h = bf16(relu( xb @ fold(W_feat) + bias2 ))
  colstats_f32_kernel<<<256, FIN, 0, stream>>>(x, NN, psum, psumsq);
  finalize_stats<<<FIN, 64, 0, stream>>>(psum, psumsq, bn_feat_g, bn_feat_b,
                                         1.0f / NN, scale, shift);
  wfold_kernel<<<HID, 256, 0, stream>>>(W_feat, scale, shift, b_feat, Wft, bias2, FIN);
  gemm_bf16_kernel<<<dim3((NN + 127) / 128, 2), 256, 0, stream>>>(
      xb, Wft, bias2, bufA, NN, FIN, 1);

  // ---- 3 GAT layers
  for (int i = 0; i < 3; ++i) {
    colstats_bf16_kernel<<<256, HID, 0, stream>>>(bufA, NN, psum, psumsq);
    finalize_stats<<<HID, 64, 0, stream>>>(psum, psumsq, bns_g + i * HID, bns_b + i * HID,
                                           1.0f / NN, scale, shift);
    wfold_kernel<<<HID, 256, 0, stream>>>(Wg + (size_t)i * HID * HID, scale, shift,
                                          nullptr, Wgt, bias2, HID);
    gemm_bf16_kernel<<<dim3((NN + 127) / 128, 2), 256, 0, stream>>>(
        bufA, Wgt, bias2, xp, NN, HID, 0);
    attn_logits_kernel<<<(NN + 3) / 4, 256, 0, stream>>>(
        xp, att_src + i * HID, att_dst + i * HID, als, ald);
    gat_agg_kernel<<<(NN + 3) / 4, 256, 0, stream>>>(rp, col, als, ald, xp,
                                                     gat_b + i * HID, bufA);
  }

  // ---- pool + tail
  hipMemsetAsync(g0, 0, (size_t)NG * HID * 4, stream);
  pool_kernel<<<256, HID, 0, stream>>>(bufA, batch, g0);
  small_bn_kernel<<<HID, NG, 0, stream>>>(g0, bn_fc_g, bn_fc_b, g1);
  small_fc_kernel<<<NG, HID, 0, stream>>>(g1, W_fc, b_fc, g0);
  small_bn_kernel<<<HID, NG, 0, stream>>>(g0, bn_h_g, bn_h_b, g1);
  cls_kernel<<<NG, HID, 0, stream>>>(g1, W_cls, b_cls, (float*)d_out);
}